// Round 6
// baseline (226.676 us; speedup 1.0000x reference)
//
#include <hip/hip_runtime.h>

typedef unsigned short u16;
typedef unsigned int   u32;
typedef __attribute__((ext_vector_type(8))) short bf16x8;
typedef __attribute__((ext_vector_type(4))) float f32x4;

#define EPSF 1e-15f

// Per-row layout inside the x input buffer (f32, row stride 128 floats = 512 B):
//   [0,32)   st as bf16 (64 values packed into 32 u32 words) [k_a; read by k_c]
//            -> after k_yd, [0,8) is REUSED for s2 packed bf16 (16 vals) [read by k_e]
//   [32,64)  y slots: only used by the ws<33MB FALLBACK path (k_y_st -> k_d2)
//   [64,96)  x1
//   112      q1 = ||st_row||^2 (bf16-rounded st)
//   113      d2 = rowsum(adjn_unscaled)
//   [114,128) spare -> batch accumulators, rows b*1024 + a/14
// Accumulator a per batch: 0 Dsum, 1 T1, 2 Tq1, 3 Pg, 4 Q2, 5 T2,
//   6..518 outm (k*32+h), 518..774 oam (k*16+l) UNSCALED, 774..1030 ssm,
//   1030..1034 per-batch loss scalars, 1035 = k_f1 last-block counter.
// Dsum/T1/Tq1 now accumulated in k_c's epilogue (decomposed over tiles) so the
// fused k_yd can read invv immediately.
// d_ws: [0,32MB) anb (packed bf16 an, [b][n][m/2] u32);
//       [32MB,33MB) x1T bf16 [b][h(32)][m(1024)] (written by k_a, read by k_yd).
__device__ __forceinline__ float* accp(float* xb, int b, int a) {
    return xb + (size_t)(b*1024 + a/14)*128 + 114 + (a % 14);
}

__device__ __forceinline__ float bf2f(u16 u) {
    union { u32 i; float f; } v; v.i = ((u32)u) << 16; return v.f;
}
__device__ __forceinline__ u16 f2bf(float f) {
    union { u32 i; float f; } v; v.f = f;
    u32 r = v.i + 0x7fffu + ((v.i >> 16) & 1u);
    return (u16)(r >> 16);
}

// ---------------- Kernel A: x1 = x@W1+b1 ; st = tanh(x1@Wp1+bp1) stored bf16;
// q1 = ||st_bf16||^2 ; zero d2 + accumulator spares. Optionally writes x1T
// (bf16, [b][h][m]) to workspace for k_yd's direct-B MFMA loads.
__global__ __launch_bounds__(256) void k_a(float* xb,
        const float* __restrict__ W1, const float* __restrict__ b1,
        const float* __restrict__ Wp1, const float* __restrict__ bp1,
        u32* __restrict__ x1t)
{
    __shared__ float W1sT[32*133];   // [col][f]
    __shared__ float Wp1sT[64*33];   // [l][h]
    __shared__ float xs[16][128];
    __shared__ float x1s[16][32];
    int tid = threadIdx.x;
    for (int i = tid; i < 1024; i += 256) {
        int f = i >> 3, c0 = (i & 7)*4;
        float4 v = *(const float4*)&W1[f*32 + c0];
        W1sT[(c0+0)*133 + f] = v.x;
        W1sT[(c0+1)*133 + f] = v.y;
        W1sT[(c0+2)*133 + f] = v.z;
        W1sT[(c0+3)*133 + f] = v.w;
    }
    for (int i = tid; i < 512; i += 256) {
        int h = i >> 4, l0 = (i & 15)*4;
        float4 v = *(const float4*)&Wp1[h*64 + l0];
        Wp1sT[(l0+0)*33 + h] = v.x;
        Wp1sT[(l0+1)*33 + h] = v.y;
        Wp1sT[(l0+2)*33 + h] = v.z;
        Wp1sT[(l0+3)*33 + h] = v.w;
    }
    int rbase = blockIdx.x*16;
    for (int e = tid; e < 512; e += 256) {
        int rr = e >> 5, c = e & 31;
        *(float4*)&xs[rr][c*4] = *(const float4*)&xb[(size_t)(rbase + rr)*128 + c*4];
    }
    __syncthreads();
    int w = tid >> 6, l = tid & 63;
    int col = l & 31, half = l >> 5;
    #pragma unroll
    for (int i = 0; i < 4; ++i) {
        int rr = w*4 + i;
        float* xr = xb + (size_t)(rbase + rr)*128;
        if (l < 15) xr[113 + l] = 0.f;
        float acc = half ? 0.f : b1[col];
        const float* xrow = &xs[rr][half*64];
        const float* wrow = &W1sT[col*133 + half*64];
        for (int f = 0; f < 64; ++f) acc += xrow[f]*wrow[f];
        acc += __shfl_down(acc, 32);
        if (l < 32) x1s[rr][l] = acc;
    }
    __syncthreads();
    // x1T bf16 write: thread l<32 handles h=l, packs 16 rows (32 B x 2 stores)
    if (x1t && tid < 32) {
        int b = rbase >> 10, mbase = rbase & 1023;
        u32 pk[8];
        #pragma unroll
        for (int i2 = 0; i2 < 8; ++i2)
            pk[i2] = (u32)f2bf(x1s[2*i2][tid]) | ((u32)f2bf(x1s[2*i2+1][tid]) << 16);
        u32* dst = x1t + (size_t)b*16384 + tid*512 + (mbase >> 1);
        *(uint4*)dst     = make_uint4(pk[0], pk[1], pk[2], pk[3]);
        *(uint4*)(dst+4) = make_uint4(pk[4], pk[5], pk[6], pk[7]);
    }
    #pragma unroll
    for (int i = 0; i < 4; ++i) {
        int rr = w*4 + i;
        float* xr = xb + (size_t)(rbase + rr)*128;
        if (l < 32) xr[64 + l] = x1s[rr][l];
        float acc = bp1[l];
        const float* wp = &Wp1sT[l*33];
        for (int h = 0; h < 32; ++h) acc += x1s[rr][h]*wp[h];
        float sv = tanhf(acc);
        u32 me = (u32)f2bf(sv);
        u32 nb = __shfl_down(me, 1);
        if (!(l & 1)) ((u32*)xr)[l >> 1] = me | (nb << 16);
        float svr = bf2f((u16)me);
        float qv = svr*svr;
        for (int off = 32; off; off >>= 1) qv += __shfl_down(qv, off);
        if (l == 0) xr[112] = qv;
    }
}

// ---------------- Kernel C (MFMA): r2 configuration (measured best: 42-44 µs).
// TWO tj tiles per block, grid (8,16,16), BufA staged, bounds(256,5).
// r3 (direct-A + 6/CU) = 55 µs via write amplification; r4 (1-tile + LDS store
// path) = 66 µs via lost memory-level parallelism. Keep this structure.
// Epilogue now also accumulates batch Dsum/T1 (all blocks) and Tq1 (tjq==0),
// decomposed over tiles -> k_yd can read invv without a separate fold kernel.
// Per-row degree atomic (xr[96]) removed: no reader remains.
__global__ __launch_bounds__(256, 5) void k_c(const float* __restrict__ adj, float* xb,
                                              u32* __restrict__ anb)
{
    __shared__ __align__(16) u16 BufA[64*72];     // st_ti
    __shared__ __align__(16) u16 BufB[2][64*72];  // st_tj (2 tiles)
    __shared__ __align__(16) float qAs[64], qBs[2][64];
    __shared__ float pw[5][4];
    int tid = threadIdx.x;
    int tjq = blockIdx.x, ti = blockIdx.y, b = blockIdx.z;
    int w = tid >> 6, lane = tid & 63;
    int q = lane >> 4, c16 = lane & 15;
    int rloc = w*16 + c16;
    size_t rowg = (size_t)(b*1024 + ti*64 + rloc);
    // adj loads first: max prefetch distance
    float4 a4s[2][4];
    #pragma unroll
    for (int tt = 0; tt < 2; ++tt)
        #pragma unroll
        for (int t = 0; t < 4; ++t)
            a4s[tt][t] = *(const float4*)&adj[rowg*1024 + (tjq*2 + tt)*64 + t*16 + q*4];
    const u32* xu = (const u32*)xb;
    for (int e = tid; e < 512; e += 256) {
        int n = e >> 3, c = e & 7;
        *(float4*)&BufA[n*72 + c*8] = *(const float4*)&xu[(size_t)(b*1024 + ti*64 + n)*128 + c*4];
    }
    for (int e = tid; e < 1024; e += 256) {
        int n2 = e >> 3, c = e & 7;
        int tt = n2 >> 6, n = n2 & 63;
        *(float4*)&BufB[tt][n*72 + c*8] =
            *(const float4*)&xu[(size_t)(b*1024 + (tjq*2 + tt)*64 + n)*128 + c*4];
    }
    if (tid < 64) qAs[tid] = xb[(size_t)(b*1024 + ti*64 + tid)*128 + 112];
    else if (tid < 192) {
        int t2 = tid - 64;
        qBs[t2 >> 6][t2 & 63] =
            xb[(size_t)(b*1024 + (tjq*2 + (t2 >> 6))*64 + (t2 & 63))*128 + 112];
    }
    __syncthreads();
    bf16x8 bfr0 = *(const bf16x8*)&BufA[rloc*72 + q*8];
    bf16x8 bfr1 = *(const bf16x8*)&BufA[rloc*72 + 32 + q*8];
    float qa = qAs[rloc];
    float dsum = 0.f, rsum = 0.f, Pt = 0.f, Qt = 0.f;
    #pragma unroll
    for (int tt = 0; tt < 2; ++tt) {
        f32x4 g[4];
        #pragma unroll
        for (int t = 0; t < 4; ++t) {
            bf16x8 af0 = *(const bf16x8*)&BufB[tt][(t*16 + c16)*72 + q*8];
            bf16x8 af1 = *(const bf16x8*)&BufB[tt][(t*16 + c16)*72 + 32 + q*8];
            f32x4 gg = {0.f, 0.f, 0.f, 0.f};
            gg = __builtin_amdgcn_mfma_f32_16x16x32_bf16(af0, bfr0, gg, 0, 0, 0);
            gg = __builtin_amdgcn_mfma_f32_16x16x32_bf16(af1, bfr1, gg, 0, 0, 0);
            g[t] = gg;
        }
        #pragma unroll
        for (int t = 0; t < 4; ++t) {
            float4 a4 = a4s[tt][t];
            float4 qb4 = *(const float4*)&qBs[tt][t*16 + q*4];
            float av[4] = {a4.x, a4.y, a4.z, a4.w};
            float qb[4] = {qb4.x, qb4.y, qb4.z, qb4.w};
            float o[4];
            #pragma unroll
            for (int rg = 0; rg < 4; ++rg) {
                float d2v = qa + qb[rg] - 2.f*g[t][rg];
                float dist = sqrtf(fmaxf(d2v, 0.f));
                o[rg] = dist * av[rg];
                dsum += av[rg];
                rsum += o[rg];
                Pt += av[rg]*g[t][rg];
                Qt += g[t][rg]*g[t][rg];
            }
            u32 p0 = (u32)f2bf(o[0]) | ((u32)f2bf(o[1]) << 16);
            u32 p1 = (u32)f2bf(o[2]) | ((u32)f2bf(o[3]) << 16);
            *(uint2*)&anb[rowg*512 + (tjq*2 + tt)*32 + t*8 + q*2] = make_uint2(p0, p1);
        }
    }
    rsum += __shfl_xor(rsum, 16); rsum += __shfl_xor(rsum, 32);
    dsum += __shfl_xor(dsum, 16); dsum += __shfl_xor(dsum, 32);
    if (q == 0) atomicAdd(&xb[rowg*128 + 113], rsum);
    // batch-level partials: Dsum, T1 = sum q1*d (tile-decomposed), Tq1 (tjq==0)
    float cd = (q == 0) ? dsum : 0.f;
    float c1 = (q == 0) ? qa*dsum : 0.f;
    float cq = (q == 0 && tjq == 0) ? qa : 0.f;
    for (int off = 32; off; off >>= 1) {
        Pt += __shfl_down(Pt, off); Qt += __shfl_down(Qt, off);
        cd += __shfl_down(cd, off); c1 += __shfl_down(c1, off); cq += __shfl_down(cq, off);
    }
    if (lane == 0) { pw[0][w]=Pt; pw[1][w]=Qt; pw[2][w]=cd; pw[3][w]=c1; pw[4][w]=cq; }
    __syncthreads();
    if (tid == 0) {
        atomicAdd(accp(xb,b,3), pw[0][0]+pw[0][1]+pw[0][2]+pw[0][3]);
        atomicAdd(accp(xb,b,4), pw[1][0]+pw[1][1]+pw[1][2]+pw[1][3]);
        atomicAdd(accp(xb,b,0), pw[2][0]+pw[2][1]+pw[2][2]+pw[2][3]);
        atomicAdd(accp(xb,b,1), pw[3][0]+pw[3][1]+pw[3][2]+pw[3][3]);
        if (tjq == 0)
            atomicAdd(accp(xb,b,2), pw[4][0]+pw[4][1]+pw[4][2]+pw[4][3]);
    }
}

// ---------------- Kernel YD (fused y + d2): grid (16 ni, 16 b), 256 threads.
// Phase 1: y = an@x1 for 64 rows, NO LDS staging, NO barriers in K-loop —
// af direct from anb (read once), bx direct from L3-resident x1T. y never
// touches HBM: ys = y*invv goes straight to LDS.
// Phase 2: old k_d2 (x2 GEMM, softmax s2, outm/ssm/T2) extended to 64 rows.
__global__ __launch_bounds__(256) void k_yd(const u32* __restrict__ anb,
        const u32* __restrict__ x1t, float* xb,
        const float* __restrict__ Wrel1, const float* __restrict__ brel1,
        const float* __restrict__ Wroot1,
        const float* __restrict__ Wp2, const float* __restrict__ bp2)
{
    __shared__ float ys[64*33];
    __shared__ float x1n[64*36];
    __shared__ float x2s[64*33];
    __shared__ float s2s[64*17];
    __shared__ float WrT[32*33], WoT[32*33], WpT[16*33];
    __shared__ float pwd[4];
    int tid = threadIdx.x;
    int ni = blockIdx.x, b = blockIdx.y;
    int rbase = b*1024 + ni*64;
    float invv = 1.f / (*accp(xb,b,0) + 1024.f*EPSF);
    {
        int j = tid >> 3, h0 = (tid & 7)*4;
        float4 v = *(const float4*)&Wrel1[j*32 + h0];
        WrT[(h0+0)*33 + j] = v.x;
        WrT[(h0+1)*33 + j] = v.y;
        WrT[(h0+2)*33 + j] = v.z;
        WrT[(h0+3)*33 + j] = v.w;
        float4 v2 = *(const float4*)&Wroot1[j*32 + h0];
        WoT[(h0+0)*33 + j] = v2.x;
        WoT[(h0+1)*33 + j] = v2.y;
        WoT[(h0+2)*33 + j] = v2.z;
        WoT[(h0+3)*33 + j] = v2.w;
    }
    if (tid < 128) {
        int j = tid >> 2, k0 = (tid & 3)*4;
        float4 v = *(const float4*)&Wp2[j*16 + k0];
        WpT[(k0+0)*33 + j] = v.x;
        WpT[(k0+1)*33 + j] = v.y;
        WpT[(k0+2)*33 + j] = v.z;
        WpT[(k0+3)*33 + j] = v.w;
    }
    for (int e = tid; e < 512; e += 256) {
        int r = e >> 3, c = e & 7;
        *(float4*)&x1n[r*36 + c*4] = *(const float4*)&xb[(size_t)(rbase + r)*128 + 64 + c*4];
    }
    // ---- phase 1: y MFMA (no barriers, direct operands)
    int w = tid >> 6, lane = tid & 63;
    int q = lane >> 4, c16 = lane & 15;
    int rloc = w*16 + c16;
    size_t rowg = (size_t)(rbase + rloc);
    const u32* xrow = x1t + (size_t)b*16384;
    f32x4 acc0 = {0.f,0.f,0.f,0.f}, acc1 = {0.f,0.f,0.f,0.f};
    #pragma unroll 8
    for (int ks = 0; ks < 32; ++ks) {
        bf16x8 af  = *(const bf16x8*)&anb[rowg*512 + ks*16 + q*4];
        bf16x8 b0  = *(const bf16x8*)&xrow[c16*512 + ks*16 + q*4];
        bf16x8 b1v = *(const bf16x8*)&xrow[(c16+16)*512 + ks*16 + q*4];
        acc0 = __builtin_amdgcn_mfma_f32_16x16x32_bf16(af, b0,  acc0, 0, 0, 0);
        acc1 = __builtin_amdgcn_mfma_f32_16x16x32_bf16(af, b1v, acc1, 0, 0, 0);
    }
    #pragma unroll
    for (int rg = 0; rg < 4; ++rg) {
        int row = w*16 + q*4 + rg;
        ys[row*33 + c16]      = acc0[rg]*invv;
        ys[row*33 + 16 + c16] = acc1[rg]*invv;
    }
    __syncthreads();
    // ---- phase 2a: x2 GEMM (64 rows)
    {
        int h = tid & 31, tg = tid >> 5;
        float brl = brel1[h];
        const float* wr = &WrT[h*33];
        const float* wo = &WoT[h*33];
        #pragma unroll
        for (int i = 0; i < 8; ++i) {
            int r = tg + 8*i;
            float v = brl;
            for (int j = 0; j < 32; ++j)
                v += ys[r*33 + j]*wr[j] + x1n[r*36 + j]*wo[j];
            x2s[r*33 + h] = v;
        }
    }
    __syncthreads();
    // ---- phase 2b: softmax s2 (2 passes of 32 rows), pack bf16 to xb[0,8)
    {
        int rl = tid & 7, kq = (tid >> 3) & 7, wv = tid >> 6;
        int k0 = kq*2;
        const float* wp0 = &WpT[k0*33];
        const float* wp1 = &WpT[(k0+1)*33];
        float denp = 0.f;
        #pragma unroll
        for (int pass = 0; pass < 2; ++pass) {
            int r = wv*8 + rl + pass*32;
            float v0 = bp2[k0], v1 = bp2[k0 + 1];
            for (int j = 0; j < 32; ++j) {
                float xv = x2s[r*33 + j];
                v0 += xv*wp0[j];
                v1 += xv*wp1[j];
            }
            float mx = fmaxf(v0, v1);
            mx = fmaxf(mx, __shfl_xor(mx, 8));
            mx = fmaxf(mx, __shfl_xor(mx, 16));
            mx = fmaxf(mx, __shfl_xor(mx, 32));
            float e0 = expf(v0 - mx), e1 = expf(v1 - mx);
            float sm = e0 + e1;
            sm += __shfl_xor(sm, 8); sm += __shfl_xor(sm, 16); sm += __shfl_xor(sm, 32);
            float inv = 1.f/sm;
            float sv0 = e0*inv, sv1 = e1*inv;
            s2s[r*17 + k0]     = sv0;
            s2s[r*17 + k0 + 1] = sv1;
            ((u32*)(xb + (size_t)(rbase + r)*128))[kq] =
                (u32)f2bf(sv0) | ((u32)f2bf(sv1) << 16);
            float q2v = sv0*sv0 + sv1*sv1;
            q2v += __shfl_xor(q2v, 8); q2v += __shfl_xor(q2v, 16); q2v += __shfl_xor(q2v, 32);
            if (kq == 0)
                denp += (xb[(size_t)(rbase + r)*128 + 113]*invv + EPSF)*q2v;
        }
        denp += __shfl_down(denp, 1);
        denp += __shfl_down(denp, 2);
        denp += __shfl_down(denp, 4);
        if ((tid & 63) == 0) pwd[wv] = denp;
    }
    __syncthreads();
    if (tid == 0) atomicAdd(accp(xb,b,5), pwd[0]+pwd[1]+pwd[2]+pwd[3]);
    {
        int k = tid >> 4, l = tid & 15;
        float s = 0.f;
        for (int r = 0; r < 64; ++r) s += s2s[r*17 + k]*s2s[r*17 + l];
        atomicAdd(accp(xb,b,774 + tid), s);
    }
    for (int e = tid; e < 512; e += 256) {
        int k = e >> 5, h = e & 31;
        float s = 0.f;
        for (int r = 0; r < 64; ++r) s += s2s[r*17 + k]*x2s[r*33 + h];
        atomicAdd(accp(xb,b,6 + k*32 + h), s);
    }
}

// ---------------- FALLBACK (ws < 33 MB): r5's staged k_y (fold stripped —
// Dsum/T1/Tq1 now come from k_c) + r5's k_d2.
__global__ __launch_bounds__(256) void k_y_st(const u32* __restrict__ anb, float* xb)
{
    __shared__ __align__(16) u16 X[16*1032];
    int tid = threadIdx.x;
    int hq = blockIdx.x, ni = blockIdx.y, b = blockIdx.z;
    int w = tid >> 6, lane = tid & 63;
    int q = lane >> 4, c16 = lane & 15;
    int rloc = w*16 + c16;
    size_t rowg = (size_t)(b*1024 + ni*64 + rloc);
    u32* Xu = (u32*)X;
    for (int e = tid; e < 2048; e += 256) {
        int mp = e >> 2, h4 = e & 3;
        int m0 = mp*2;
        const float* p0 = &xb[(size_t)(b*1024 + m0)*128 + 64 + hq*16 + h4*4];
        float4 v0 = *(const float4*)p0;
        float4 v1 = *(const float4*)(p0 + 128);
        Xu[(h4*4 + 0)*516 + mp] = (u32)f2bf(v0.x) | ((u32)f2bf(v1.x) << 16);
        Xu[(h4*4 + 1)*516 + mp] = (u32)f2bf(v0.y) | ((u32)f2bf(v1.y) << 16);
        Xu[(h4*4 + 2)*516 + mp] = (u32)f2bf(v0.z) | ((u32)f2bf(v1.z) << 16);
        Xu[(h4*4 + 3)*516 + mp] = (u32)f2bf(v0.w) | ((u32)f2bf(v1.w) << 16);
    }
    __syncthreads();
    f32x4 acc = {0.f,0.f,0.f,0.f};
    #pragma unroll 8
    for (int ks = 0; ks < 32; ++ks) {
        bf16x8 af = *(const bf16x8*)&anb[rowg*512 + ks*16 + q*4];
        bf16x8 bx = *(const bf16x8*)&X[c16*1032 + ks*32 + q*8];
        acc = __builtin_amdgcn_mfma_f32_16x16x32_bf16(af, bx, acc, 0, 0, 0);
    }
    #pragma unroll
    for (int rg = 0; rg < 4; ++rg) {
        size_t orow = (size_t)(b*1024 + ni*64 + w*16 + q*4 + rg)*128;
        xb[orow + 32 + hq*16 + c16] = acc[rg];
    }
}

__global__ __launch_bounds__(256) void k_d2(float* xb,
        const float* __restrict__ Wrel1, const float* __restrict__ brel1,
        const float* __restrict__ Wroot1,
        const float* __restrict__ Wp2, const float* __restrict__ bp2)
{
    __shared__ float ys[32*34];
    __shared__ float x1n[32*34];
    __shared__ float x2s[32*34];
    __shared__ float s2s[32*17];
    __shared__ float WrT[32*33], WoT[32*33], WpT[16*33];
    __shared__ float pwd[4];
    int tid = threadIdx.x;
    int tq = blockIdx.x, b = blockIdx.y;
    int rbase = b*1024 + tq*32;
    float invv = 1.f / (*accp(xb,b,0) + 1024.f*EPSF);
    {
        int j = tid >> 3, h0 = (tid & 7)*4;
        float4 v = *(const float4*)&Wrel1[j*32 + h0];
        WrT[(h0+0)*33 + j] = v.x;
        WrT[(h0+1)*33 + j] = v.y;
        WrT[(h0+2)*33 + j] = v.z;
        WrT[(h0+3)*33 + j] = v.w;
        float4 v2 = *(const float4*)&Wroot1[j*32 + h0];
        WoT[(h0+0)*33 + j] = v2.x;
        WoT[(h0+1)*33 + j] = v2.y;
        WoT[(h0+2)*33 + j] = v2.z;
        WoT[(h0+3)*33 + j] = v2.w;
    }
    if (tid < 128) {
        int j = tid >> 2, k0 = (tid & 3)*4;
        float4 v = *(const float4*)&Wp2[j*16 + k0];
        WpT[(k0+0)*33 + j] = v.x;
        WpT[(k0+1)*33 + j] = v.y;
        WpT[(k0+2)*33 + j] = v.z;
        WpT[(k0+3)*33 + j] = v.w;
    }
    for (int e = tid; e < 1024; e += 256) {
        int r = e >> 5, h = e & 31;
        const float* xr = xb + (size_t)(rbase + r)*128;
        ys[r*34 + h]  = xr[32 + h] * invv;
        x1n[r*34 + h] = xr[64 + h];
    }
    __syncthreads();
    {
        int h = tid & 31, tg = tid >> 5;
        float brl = brel1[h];
        const float* wr = &WrT[h*33];
        const float* wo = &WoT[h*33];
        #pragma unroll
        for (int i = 0; i < 4; ++i) {
            int r = tg + 8*i;
            float v = brl;
            for (int j = 0; j < 32; ++j)
                v += ys[r*34 + j]*wr[j] + x1n[r*34 + j]*wo[j];
            x2s[r*34 + h] = v;
        }
    }
    __syncthreads();
    {
        int rl = tid & 7, kq = (tid >> 3) & 7, wv = tid >> 6;
        int r = wv*8 + rl;
        int k0 = kq*2;
        float v0 = bp2[k0], v1 = bp2[k0 + 1];
        const float* wp0 = &WpT[k0*33];
        const float* wp1 = &WpT[(k0+1)*33];
        for (int j = 0; j < 32; ++j) {
            float xv = x2s[r*34 + j];
            v0 += xv*wp0[j];
            v1 += xv*wp1[j];
        }
        float mx = fmaxf(v0, v1);
        mx = fmaxf(mx, __shfl_xor(mx, 8));
        mx = fmaxf(mx, __shfl_xor(mx, 16));
        mx = fmaxf(mx, __shfl_xor(mx, 32));
        float e0 = expf(v0 - mx), e1 = expf(v1 - mx);
        float sm = e0 + e1;
        sm += __shfl_xor(sm, 8); sm += __shfl_xor(sm, 16); sm += __shfl_xor(sm, 32);
        float inv = 1.f/sm;
        float sv0 = e0*inv, sv1 = e1*inv;
        s2s[r*17 + k0]     = sv0;
        s2s[r*17 + k0 + 1] = sv1;
        ((u32*)(xb + (size_t)(rbase + r)*128))[kq] =
            (u32)f2bf(sv0) | ((u32)f2bf(sv1) << 16);
        float q2v = sv0*sv0 + sv1*sv1;
        q2v += __shfl_xor(q2v, 8); q2v += __shfl_xor(q2v, 16); q2v += __shfl_xor(q2v, 32);
        float denp = (kq == 0)
            ? (xb[(size_t)(rbase + r)*128 + 113]*invv + EPSF)*q2v : 0.f;
        denp += __shfl_down(denp, 1);
        denp += __shfl_down(denp, 2);
        denp += __shfl_down(denp, 4);
        if ((tid & 63) == 0) pwd[wv] = denp;
    }
    __syncthreads();
    if (tid == 0) atomicAdd(accp(xb,b,5), pwd[0]+pwd[1]+pwd[2]+pwd[3]);
    {
        int k = tid >> 4, l = tid & 15;
        float s = 0.f;
        for (int r = 0; r < 32; ++r) s += s2s[r*17 + k]*s2s[r*17 + l];
        atomicAdd(accp(xb,b,774 + tid), s);
    }
    for (int e = tid; e < 512; e += 256) {
        int k = e >> 5, h = e & 31;
        float s = 0.f;
        for (int r = 0; r < 32; ++r) s += s2s[r*17 + k]*x2s[r*34 + h];
        atomicAdd(accp(xb,b,6 + k*32 + h), s);
    }
}

// ---------------- Kernel E (MFMA): block (miq,ni,b), 2 mi tiles, grid (8,16,16).
__global__ __launch_bounds__(256) void k_e(const u32* __restrict__ anb, float* xb)
{
    __shared__ __align__(16) u16 BufS[2][16*72];
    __shared__ __align__(16) u16 BufN[16*72];
    __shared__ __align__(16) u16 zT[16*72];
    int tid = threadIdx.x;
    int miq = blockIdx.x, ni = blockIdx.y, b = blockIdx.z;
    const u32* xu = (const u32*)xb;
    for (int e = tid; e < 512; e += 256) {
        int node = e >> 3, lw = e & 7;
        u32 pp = xu[(size_t)(b*1024 + ni*64 + node)*128 + lw];
        BufN[(lw*2)*72 + node]     = (u16)pp;
        BufN[(lw*2 + 1)*72 + node] = (u16)(pp >> 16);
    }
    for (int e = tid; e < 1024; e += 256) {
        int t = e >> 9, e2 = e & 511;
        int node = e2 >> 3, lw = e2 & 7;
        u32 pp = xu[(size_t)(b*1024 + (miq*2 + t)*64 + node)*128 + lw];
        BufS[t][(lw*2)*72 + node]     = (u16)pp;
        BufS[t][(lw*2 + 1)*72 + node] = (u16)(pp >> 16);
    }
    int w = tid >> 6, lane = tid & 63;
    int q = lane >> 4, c16 = lane & 15;
    int rloc = w*16 + c16;
    size_t arow = (size_t)(b*1024 + ni*64 + rloc)*512;
    bf16x8 ya[2][2];
    #pragma unroll
    for (int t = 0; t < 2; ++t) {
        ya[t][0] = *(const bf16x8*)&anb[arow + (miq*2 + t)*32 + q*4];
        ya[t][1] = *(const bf16x8*)&anb[arow + (miq*2 + t)*32 + 16 + q*4];
    }
    __syncthreads();
    f32x4 zacc = {0.f, 0.f, 0.f, 0.f};
    #pragma unroll
    for (int t = 0; t < 2; ++t) {
        bf16x8 yb0 = *(const bf16x8*)&BufS[t][c16*72 + q*8];
        bf16x8 yb1 = *(const bf16x8*)&BufS[t][c16*72 + 32 + q*8];
        zacc = __builtin_amdgcn_mfma_f32_16x16x32_bf16(ya[t][0], yb0, zacc, 0, 0, 0);
        zacc = __builtin_amdgcn_mfma_f32_16x16x32_bf16(ya[t][1], yb1, zacc, 0, 0, 0);
    }
    #pragma unroll
    for (int rg = 0; rg < 4; ++rg)
        zT[c16*72 + w*16 + q*4 + rg] = f2bf(zacc[rg]);
    __syncthreads();
    if (w == 0) {
        bf16x8 af0 = *(const bf16x8*)&BufN[c16*72 + q*8];
        bf16x8 af1 = *(const bf16x8*)&BufN[c16*72 + 32 + q*8];
        bf16x8 bz0 = *(const bf16x8*)&zT[c16*72 + q*8];
        bf16x8 bz1 = *(const bf16x8*)&zT[c16*72 + 32 + q*8];
        f32x4 oamv = {0.f, 0.f, 0.f, 0.f};
        oamv = __builtin_amdgcn_mfma_f32_16x16x32_bf16(af0, bz0, oamv, 0, 0, 0);
        oamv = __builtin_amdgcn_mfma_f32_16x16x32_bf16(af1, bz1, oamv, 0, 0, 0);
        #pragma unroll
        for (int rg = 0; rg < 4; ++rg)
            atomicAdd(accp(xb, b, 518 + (q*4 + rg)*16 + c16), oamv[rg]);
    }
}

// ---------------- Kernel F1: per-batch finalize (grid 16) + last-block scalar fold.
__global__ __launch_bounds__(256) void k_f1(float* xb,
        const float* __restrict__ Wrel2, const float* __restrict__ brel2,
        const float* __restrict__ Wroot2,
        const float* __restrict__ W_lin2, const float* __restrict__ b_lin2,
        const float* __restrict__ W_lin3, const float* __restrict__ b_lin3,
        float* __restrict__ outp)
{
    __shared__ float oam_s[256], ssm_s[256], outm_s[512];
    __shared__ float dks[16], csoa[16];
    __shared__ float cs0[32], cs1[32], xsum[32], x5[32], lgs[10];
    __shared__ float red[4];
    __shared__ int isLast;
    int b = blockIdx.x;
    int tid = threadIdx.x;
    float invv = 1.f / (*accp(xb,b,0) + 1024.f*EPSF);
    oam_s[tid] = *accp(xb,b,518 + tid) * invv;
    ssm_s[tid] = *accp(xb,b,774 + tid);
    for (int e = tid; e < 512; e += 256) outm_s[e] = *accp(xb,b,6 + e);
    __syncthreads();
    if (tid < 16) {
        float rsv = 0.f;
        for (int l = 0; l < 16; ++l) if (l != tid) rsv += oam_s[tid*16 + l];
        dks[tid] = sqrtf(fmaxf(rsv, 0.f) + EPSF) + EPSF;
    }
    {
        float v = ssm_s[tid];
        float p = v*v;
        for (int off = 32; off; off >>= 1) p += __shfl_down(p, off);
        if ((tid & 63) == 0) red[tid >> 6] = p;
    }
    __syncthreads();
    if (tid < 16) {
        float s = 0.f;
        for (int k2 = 0; k2 < 16; ++k2)
            if (k2 != tid) s += oam_s[k2*16 + tid] / dks[k2];
        csoa[tid] = s / dks[tid];
    }
    if (tid < 32) {
        float s0 = 0.f, s1 = 0.f;
        for (int l = 0; l < 16; ++l) {
            float ov = outm_s[l*32 + tid];
            s0 += ov;
            s1 += csoa[l] * ov;   // same wave as csoa writers; intra-wave order holds
        }
        cs0[tid] = s0; cs1[tid] = s1;
    }
    if (tid == 64) {
        float T1v  = *accp(xb,b,1);
        float Pgv  = *accp(xb,b,3);
        float Q2v  = *accp(xb,b,4);
        float Tq1v = *accp(xb,b,2);
        float T2v  = *accp(xb,b,5);
        float tr2 = 0.f, trs = 0.f;
        for (int k2 = 0; k2 < 16; ++k2) { tr2 += oam_s[k2*17]; trs += ssm_s[k2*17]; }
        float fr2 = red[0] + red[1] + red[2] + red[3];
        __hip_atomic_store(accp(xb,b,1030), (T1v - Pgv) / (T1v + EPSF),
                           __ATOMIC_RELAXED, __HIP_MEMORY_SCOPE_AGENT);
        __hip_atomic_store(accp(xb,b,1031), 65.f - 2.f*Tq1v/sqrtf(fmaxf(Q2v, 1e-30f)),
                           __ATOMIC_RELAXED, __HIP_MEMORY_SCOPE_AGENT);
        __hip_atomic_store(accp(xb,b,1032), -tr2 / T2v,
                           __ATOMIC_RELAXED, __HIP_MEMORY_SCOPE_AGENT);
        __hip_atomic_store(accp(xb,b,1033),
                           sqrtf(fmaxf(2.f - trs/(2.f*sqrtf(fmaxf(fr2, 1e-30f))), 0.f)),
                           __ATOMIC_RELAXED, __HIP_MEMORY_SCOPE_AGENT);
    }
    __syncthreads();
    if (tid < 32) {
        float v = 16.f * brel2[tid];
        for (int j = 0; j < 32; ++j)
            v += cs1[j]*Wrel2[j*32 + tid] + cs0[j]*Wroot2[j*32 + tid];
        xsum[tid] = v;
    }
    __syncthreads();
    if (tid < 32) {
        float v = b_lin2[tid];
        for (int j = 0; j < 32; ++j) v += xsum[j]*W_lin2[j*32 + tid];
        x5[tid] = fmaxf(v, 0.f);
    }
    __syncthreads();
    if (tid < 10) {
        float v = b_lin3[tid];
        for (int j = 0; j < 32; ++j) v += x5[j]*W_lin3[j*10 + tid];
        lgs[tid] = v;
    }
    __syncthreads();
    if (tid < 10) {
        float mx = -1e30f;
        for (int t = 0; t < 10; ++t) mx = fmaxf(mx, lgs[t]);
        float sum = 0.f;
        for (int t = 0; t < 10; ++t) sum += expf(lgs[t] - mx);
        outp[b*10 + tid] = lgs[tid] - mx - logf(sum);
    }
    __syncthreads();
    if (tid == 0) {
        __threadfence();
        float old = atomicAdd(accp(xb,0,1035), 1.f);
        isLast = (old > 14.5f) ? 1 : 0;
    }
    __syncthreads();
    if (isLast && tid < 64) {
        __threadfence();
        int b2 = tid & 15, which = tid >> 4;
        float v = __hip_atomic_load(accp(xb,b2,1030 + which),
                                    __ATOMIC_RELAXED, __HIP_MEMORY_SCOPE_AGENT);
        for (int off = 1; off < 16; off <<= 1) v += __shfl_xor(v, off);
        float ct = __shfl(v, 0);
        float o1 = __shfl(v, 16);
        float mc = __shfl(v, 32);
        float o2 = __shfl(v, 48);
        if (tid == 0) {
            outp[160] = ct/16.f + sqrtf(fmaxf(o1, 0.f));
            outp[161] = mc/16.f + o2/16.f;
        }
    }
}

extern "C" void kernel_launch(void* const* d_in, const int* in_sizes, int n_in,
                              void* d_out, int out_size, void* d_ws, size_t ws_size,
                              hipStream_t stream)
{
    float* xb        = (float*)d_in[0];   // x, reused as scratch (restored by harness)
    const float* adj = (const float*)d_in[1];   // READ-ONLY
    const float* W_lin1 = (const float*)d_in[3];
    const float* b_lin1 = (const float*)d_in[4];
    const float* W_pool1= (const float*)d_in[5];
    const float* b_pool1= (const float*)d_in[6];
    const float* W_pool2= (const float*)d_in[7];
    const float* b_pool2= (const float*)d_in[8];
    const float* Wrel1  = (const float*)d_in[9];
    const float* brel1  = (const float*)d_in[10];
    const float* Wroot1 = (const float*)d_in[11];
    const float* Wrel2  = (const float*)d_in[12];
    const float* brel2  = (const float*)d_in[13];
    const float* Wroot2 = (const float*)d_in[14];
    const float* W_lin2 = (const float*)d_in[15];
    const float* b_lin2 = (const float*)d_in[16];
    const float* W_lin3 = (const float*)d_in[17];
    const float* b_lin3 = (const float*)d_in[18];
    u32* anb = (u32*)d_ws;   // 32 MB, fully overwritten by k_c
    bool hasX = ws_size >= (((size_t)33) << 20);
    u32* x1t = hasX ? anb + (size_t)8*1024*1024 : (u32*)nullptr;  // +32 MB, 1 MB
    (void)in_sizes; (void)n_in; (void)out_size;

    k_a<<<dim3(1024),      dim3(256), 0, stream>>>(xb, W_lin1, b_lin1, W_pool1, b_pool1,
                                                   x1t);
    k_c<<<dim3(8,16,16),   dim3(256), 0, stream>>>(adj, xb, anb);
    if (hasX) {
        k_yd<<<dim3(16,16), dim3(256), 0, stream>>>(anb, x1t, xb, Wrel1, brel1, Wroot1,
                                                    W_pool2, b_pool2);
    } else {
        k_y_st<<<dim3(2,16,16), dim3(256), 0, stream>>>(anb, xb);
        k_d2<<<dim3(32,16),     dim3(256), 0, stream>>>(xb, Wrel1, brel1, Wroot1,
                                                        W_pool2, b_pool2);
    }
    k_e<<<dim3(8,16,16),   dim3(256), 0, stream>>>(anb, xb);
    k_f1<<<dim3(16),       dim3(256), 0, stream>>>(xb, Wrel2, brel2, Wroot2,
                                                   W_lin2, b_lin2, W_lin3, b_lin3,
                                                   (float*)d_out);
}

// Round 8
// 221.256 us; speedup vs baseline: 1.0245x; 1.0245x over previous
//
#include <hip/hip_runtime.h>

typedef unsigned short u16;
typedef unsigned int   u32;
typedef __attribute__((ext_vector_type(8))) short bf16x8;
typedef __attribute__((ext_vector_type(4))) float f32x4;

#define EPSF 1e-15f

// Per-row layout inside the x input buffer (f32, row stride 128 floats = 512 B):
//   [0,32)   st as bf16 (64 values packed into 32 u32 words) [k_a; read by k_c]
//            -> after k_yd/k_d2, [0,8) REUSED for s2 packed bf16 [read by k_e]
//   [32,64)  y slots: only used by the ws<33MB FALLBACK path (k_y_st -> k_d2)
//   [64,96)  x1
//   112      q1 = ||st_row||^2 (bf16-rounded st)
//   113      d2 = rowsum(adjn_unscaled)
//   [114,128) spare -> batch accumulators, rows b*1024 + a/14
// Accumulator slots (a): 6..518 outm (k*32+h), 518..774 oam UNSCALED,
//   774..1030 ssm, 1030..1033 loss scalars, 1035 k_f1 counter.
//   Batch scalars live in DISTINCT cache lines (r6 lesson: slots 0..5 shared
//   one 64B line -> 640 serialized atomics/line -> k_c +7 µs):
//   1050 Dsum (row75), 1064 T1 (row76), 1078 Tq1 (row77), 1092 Pg (row78),
//   1106 Q2 (row79), 1120 T2 (row80). All zeroed by k_a's row-tail zeroing.
// d_ws: [0,32MB) anb (packed bf16 an, [b][n][m/2] u32);
//       [32MB,33MB) x1T bf16 [b][h(32)][m(1024)] (k_a -> k_yd), if ws allows.
__device__ __forceinline__ float* accp(float* xb, int b, int a) {
    return xb + (size_t)(b*1024 + a/14)*128 + 114 + (a % 14);
}

__device__ __forceinline__ float bf2f(u16 u) {
    union { u32 i; float f; } v; v.i = ((u32)u) << 16; return v.f;
}
__device__ __forceinline__ u16 f2bf(float f) {
    union { u32 i; float f; } v; v.f = f;
    u32 r = v.i + 0x7fffu + ((v.i >> 16) & 1u);
    return (u16)(r >> 16);
}

// ---------------- Kernel A: x1 = x@W1+b1 ; st = tanh(x1@Wp1+bp1) stored bf16;
// q1 = ||st_bf16||^2 ; zero d2 + accumulator spares. Optionally writes x1T.
__global__ __launch_bounds__(256) void k_a(float* xb,
        const float* __restrict__ W1, const float* __restrict__ b1,
        const float* __restrict__ Wp1, const float* __restrict__ bp1,
        u32* __restrict__ x1t)
{
    __shared__ float W1sT[32*133];   // [col][f]
    __shared__ float Wp1sT[64*33];   // [l][h]
    __shared__ float xs[16][128];
    __shared__ float x1s[16][32];
    int tid = threadIdx.x;
    for (int i = tid; i < 1024; i += 256) {
        int f = i >> 3, c0 = (i & 7)*4;
        float4 v = *(const float4*)&W1[f*32 + c0];
        W1sT[(c0+0)*133 + f] = v.x;
        W1sT[(c0+1)*133 + f] = v.y;
        W1sT[(c0+2)*133 + f] = v.z;
        W1sT[(c0+3)*133 + f] = v.w;
    }
    for (int i = tid; i < 512; i += 256) {
        int h = i >> 4, l0 = (i & 15)*4;
        float4 v = *(const float4*)&Wp1[h*64 + l0];
        Wp1sT[(l0+0)*33 + h] = v.x;
        Wp1sT[(l0+1)*33 + h] = v.y;
        Wp1sT[(l0+2)*33 + h] = v.z;
        Wp1sT[(l0+3)*33 + h] = v.w;
    }
    int rbase = blockIdx.x*16;
    for (int e = tid; e < 512; e += 256) {
        int rr = e >> 5, c = e & 31;
        *(float4*)&xs[rr][c*4] = *(const float4*)&xb[(size_t)(rbase + rr)*128 + c*4];
    }
    __syncthreads();
    int w = tid >> 6, l = tid & 63;
    int col = l & 31, half = l >> 5;
    #pragma unroll
    for (int i = 0; i < 4; ++i) {
        int rr = w*4 + i;
        float* xr = xb + (size_t)(rbase + rr)*128;
        if (l < 15) xr[113 + l] = 0.f;
        float acc = half ? 0.f : b1[col];
        const float* xrow = &xs[rr][half*64];
        const float* wrow = &W1sT[col*133 + half*64];
        for (int f = 0; f < 64; ++f) acc += xrow[f]*wrow[f];
        acc += __shfl_down(acc, 32);
        if (l < 32) x1s[rr][l] = acc;
    }
    __syncthreads();
    if (x1t && tid < 32) {
        int b = rbase >> 10, mbase = rbase & 1023;
        u32 pk[8];
        #pragma unroll
        for (int i2 = 0; i2 < 8; ++i2)
            pk[i2] = (u32)f2bf(x1s[2*i2][tid]) | ((u32)f2bf(x1s[2*i2+1][tid]) << 16);
        u32* dst = x1t + (size_t)b*16384 + tid*512 + (mbase >> 1);
        *(uint4*)dst     = make_uint4(pk[0], pk[1], pk[2], pk[3]);
        *(uint4*)(dst+4) = make_uint4(pk[4], pk[5], pk[6], pk[7]);
    }
    #pragma unroll
    for (int i = 0; i < 4; ++i) {
        int rr = w*4 + i;
        float* xr = xb + (size_t)(rbase + rr)*128;
        if (l < 32) xr[64 + l] = x1s[rr][l];
        float acc = bp1[l];
        const float* wp = &Wp1sT[l*33];
        for (int h = 0; h < 32; ++h) acc += x1s[rr][h]*wp[h];
        float sv = tanhf(acc);
        u32 me = (u32)f2bf(sv);
        u32 nb = __shfl_down(me, 1);
        if (!(l & 1)) ((u32*)xr)[l >> 1] = me | (nb << 16);
        float svr = bf2f((u16)me);
        float qv = svr*svr;
        for (int off = 32; off; off >>= 1) qv += __shfl_down(qv, off);
        if (l == 0) xr[112] = qv;
    }
}

// ---------------- Kernel C (MFMA): r2/r5 configuration (measured best 42-44 µs).
// TWO tj tiles per block, grid (8,16,16), BufA staged, bounds(256,5).
// r3 (direct-A + 6/CU) = 55 µs write amplification; r4 (1-tile LDS store) = 66 µs
// lost MLP; r6 (batch scalars on one line) = 49 µs atomic serialization.
// Epilogue folds Dsum/T1/Tq1 with one-line-per-scalar slots.
__global__ __launch_bounds__(256, 5) void k_c(const float* __restrict__ adj, float* xb,
                                              u32* __restrict__ anb)
{
    __shared__ __align__(16) u16 BufA[64*72];     // st_ti
    __shared__ __align__(16) u16 BufB[2][64*72];  // st_tj (2 tiles)
    __shared__ __align__(16) float qAs[64], qBs[2][64];
    __shared__ float pw[5][4];
    int tid = threadIdx.x;
    int tjq = blockIdx.x, ti = blockIdx.y, b = blockIdx.z;
    int w = tid >> 6, lane = tid & 63;
    int q = lane >> 4, c16 = lane & 15;
    int rloc = w*16 + c16;
    size_t rowg = (size_t)(b*1024 + ti*64 + rloc);
    float4 a4s[2][4];
    #pragma unroll
    for (int tt = 0; tt < 2; ++tt)
        #pragma unroll
        for (int t = 0; t < 4; ++t)
            a4s[tt][t] = *(const float4*)&adj[rowg*1024 + (tjq*2 + tt)*64 + t*16 + q*4];
    const u32* xu = (const u32*)xb;
    for (int e = tid; e < 512; e += 256) {
        int n = e >> 3, c = e & 7;
        *(float4*)&BufA[n*72 + c*8] = *(const float4*)&xu[(size_t)(b*1024 + ti*64 + n)*128 + c*4];
    }
    for (int e = tid; e < 1024; e += 256) {
        int n2 = e >> 3, c = e & 7;
        int tt = n2 >> 6, n = n2 & 63;
        *(float4*)&BufB[tt][n*72 + c*8] =
            *(const float4*)&xu[(size_t)(b*1024 + (tjq*2 + tt)*64 + n)*128 + c*4];
    }
    if (tid < 64) qAs[tid] = xb[(size_t)(b*1024 + ti*64 + tid)*128 + 112];
    else if (tid < 192) {
        int t2 = tid - 64;
        qBs[t2 >> 6][t2 & 63] =
            xb[(size_t)(b*1024 + (tjq*2 + (t2 >> 6))*64 + (t2 & 63))*128 + 112];
    }
    __syncthreads();
    bf16x8 bfr0 = *(const bf16x8*)&BufA[rloc*72 + q*8];
    bf16x8 bfr1 = *(const bf16x8*)&BufA[rloc*72 + 32 + q*8];
    float qa = qAs[rloc];
    float dsum = 0.f, rsum = 0.f, Pt = 0.f, Qt = 0.f;
    #pragma unroll
    for (int tt = 0; tt < 2; ++tt) {
        f32x4 g[4];
        #pragma unroll
        for (int t = 0; t < 4; ++t) {
            bf16x8 af0 = *(const bf16x8*)&BufB[tt][(t*16 + c16)*72 + q*8];
            bf16x8 af1 = *(const bf16x8*)&BufB[tt][(t*16 + c16)*72 + 32 + q*8];
            f32x4 gg = {0.f, 0.f, 0.f, 0.f};
            gg = __builtin_amdgcn_mfma_f32_16x16x32_bf16(af0, bfr0, gg, 0, 0, 0);
            gg = __builtin_amdgcn_mfma_f32_16x16x32_bf16(af1, bfr1, gg, 0, 0, 0);
            g[t] = gg;
        }
        #pragma unroll
        for (int t = 0; t < 4; ++t) {
            float4 a4 = a4s[tt][t];
            float4 qb4 = *(const float4*)&qBs[tt][t*16 + q*4];
            float av[4] = {a4.x, a4.y, a4.z, a4.w};
            float qb[4] = {qb4.x, qb4.y, qb4.z, qb4.w};
            float o[4];
            #pragma unroll
            for (int rg = 0; rg < 4; ++rg) {
                float d2v = qa + qb[rg] - 2.f*g[t][rg];
                float dist = sqrtf(fmaxf(d2v, 0.f));
                o[rg] = dist * av[rg];
                dsum += av[rg];
                rsum += o[rg];
                Pt += av[rg]*g[t][rg];
                Qt += g[t][rg]*g[t][rg];
            }
            u32 p0 = (u32)f2bf(o[0]) | ((u32)f2bf(o[1]) << 16);
            u32 p1 = (u32)f2bf(o[2]) | ((u32)f2bf(o[3]) << 16);
            *(uint2*)&anb[rowg*512 + (tjq*2 + tt)*32 + t*8 + q*2] = make_uint2(p0, p1);
        }
    }
    rsum += __shfl_xor(rsum, 16); rsum += __shfl_xor(rsum, 32);
    dsum += __shfl_xor(dsum, 16); dsum += __shfl_xor(dsum, 32);
    if (q == 0) atomicAdd(&xb[rowg*128 + 113], rsum);
    float cd = (q == 0) ? dsum : 0.f;
    float c1 = (q == 0) ? qa*dsum : 0.f;
    float cq = (q == 0 && tjq == 0) ? qa : 0.f;
    for (int off = 32; off; off >>= 1) {
        Pt += __shfl_down(Pt, off); Qt += __shfl_down(Qt, off);
        cd += __shfl_down(cd, off); c1 += __shfl_down(c1, off); cq += __shfl_down(cq, off);
    }
    if (lane == 0) { pw[0][w]=Pt; pw[1][w]=Qt; pw[2][w]=cd; pw[3][w]=c1; pw[4][w]=cq; }
    __syncthreads();
    if (tid == 0) {
        atomicAdd(accp(xb,b,1092), pw[0][0]+pw[0][1]+pw[0][2]+pw[0][3]);  // Pg
        atomicAdd(accp(xb,b,1106), pw[1][0]+pw[1][1]+pw[1][2]+pw[1][3]);  // Q2
        atomicAdd(accp(xb,b,1050), pw[2][0]+pw[2][1]+pw[2][2]+pw[2][3]);  // Dsum
        atomicAdd(accp(xb,b,1064), pw[3][0]+pw[3][1]+pw[3][2]+pw[3][3]);  // T1
        if (tjq == 0)
            atomicAdd(accp(xb,b,1078), pw[4][0]+pw[4][1]+pw[4][2]+pw[4][3]);  // Tq1
    }
}

// ---------------- Kernel YD (fused y + d2): 32 rows/block, grid (32,16) = 512
// blocks -> 2 blocks/CU (r6's 64-row version ran 1 block/CU = no latency hiding).
// Phase 1: y = an@x1 via 2x2 wave tiling (wave w: row-half w&1, h-half w>>1),
// direct loads (anb own rows, L3-resident x1T); per-element MFMA chain identical
// to r5/r6 -> bit-identical y; ys = y*invv straight to LDS (y never hits HBM).
// Phase 2: r5's k_d2 on the same 32 rows.
__global__ __launch_bounds__(256) void k_yd(const u32* __restrict__ anb,
        const u32* __restrict__ x1t, float* xb,
        const float* __restrict__ Wrel1, const float* __restrict__ brel1,
        const float* __restrict__ Wroot1,
        const float* __restrict__ Wp2, const float* __restrict__ bp2)
{
    __shared__ float ys[32*33];
    __shared__ float x1n[32*34];
    __shared__ float x2s[32*34];
    __shared__ float s2s[32*17];
    __shared__ float WrT[32*33], WoT[32*33], WpT[16*33];
    __shared__ float pwd[4];
    int tid = threadIdx.x;
    int tq = blockIdx.x, b = blockIdx.y;
    int rbase = b*1024 + tq*32;
    float invv = 1.f / (*accp(xb,b,1050) + 1024.f*EPSF);
    {
        int j = tid >> 3, h0 = (tid & 7)*4;
        float4 v = *(const float4*)&Wrel1[j*32 + h0];
        WrT[(h0+0)*33 + j] = v.x;
        WrT[(h0+1)*33 + j] = v.y;
        WrT[(h0+2)*33 + j] = v.z;
        WrT[(h0+3)*33 + j] = v.w;
        float4 v2 = *(const float4*)&Wroot1[j*32 + h0];
        WoT[(h0+0)*33 + j] = v2.x;
        WoT[(h0+1)*33 + j] = v2.y;
        WoT[(h0+2)*33 + j] = v2.z;
        WoT[(h0+3)*33 + j] = v2.w;
    }
    if (tid < 128) {
        int j = tid >> 2, k0 = (tid & 3)*4;
        float4 v = *(const float4*)&Wp2[j*16 + k0];
        WpT[(k0+0)*33 + j] = v.x;
        WpT[(k0+1)*33 + j] = v.y;
        WpT[(k0+2)*33 + j] = v.z;
        WpT[(k0+3)*33 + j] = v.w;
    }
    {
        int r = tid >> 3, c = tid & 7;
        *(float4*)&x1n[r*34 + c*4] = *(const float4*)&xb[(size_t)(rbase + r)*128 + 64 + c*4];
    }
    // ---- phase 1: y MFMA, no barriers in K-loop
    int w = tid >> 6, lane = tid & 63;
    int q = lane >> 4, c16 = lane & 15;
    int rh = w & 1, hh = w >> 1;
    size_t rowg = (size_t)(rbase + rh*16 + c16);
    const u32* xrow = x1t + (size_t)b*16384 + (size_t)(hh*16 + c16)*512;
    f32x4 acc = {0.f,0.f,0.f,0.f};
    #pragma unroll 8
    for (int ks = 0; ks < 32; ++ks) {
        bf16x8 af = *(const bf16x8*)&anb[rowg*512 + ks*16 + q*4];
        bf16x8 bx = *(const bf16x8*)&xrow[ks*16 + q*4];
        acc = __builtin_amdgcn_mfma_f32_16x16x32_bf16(af, bx, acc, 0, 0, 0);
    }
    #pragma unroll
    for (int rg = 0; rg < 4; ++rg)
        ys[(rh*16 + q*4 + rg)*33 + hh*16 + c16] = acc[rg]*invv;
    __syncthreads();
    // ---- phase 2a: x2 GEMM
    {
        int h = tid & 31, tg = tid >> 5;
        float brl = brel1[h];
        const float* wr = &WrT[h*33];
        const float* wo = &WoT[h*33];
        #pragma unroll
        for (int i = 0; i < 4; ++i) {
            int r = tg + 8*i;
            float v = brl;
            for (int j = 0; j < 32; ++j)
                v += ys[r*33 + j]*wr[j] + x1n[r*34 + j]*wo[j];
            x2s[r*34 + h] = v;
        }
    }
    __syncthreads();
    // ---- phase 2b: softmax s2, pack bf16 to xb[0,8)
    {
        int rl = tid & 7, kq = (tid >> 3) & 7, wv = tid >> 6;
        int r = wv*8 + rl;
        int k0 = kq*2;
        float v0 = bp2[k0], v1 = bp2[k0 + 1];
        const float* wp0 = &WpT[k0*33];
        const float* wp1 = &WpT[(k0+1)*33];
        for (int j = 0; j < 32; ++j) {
            float xv = x2s[r*34 + j];
            v0 += xv*wp0[j];
            v1 += xv*wp1[j];
        }
        float mx = fmaxf(v0, v1);
        mx = fmaxf(mx, __shfl_xor(mx, 8));
        mx = fmaxf(mx, __shfl_xor(mx, 16));
        mx = fmaxf(mx, __shfl_xor(mx, 32));
        float e0 = expf(v0 - mx), e1 = expf(v1 - mx);
        float sm = e0 + e1;
        sm += __shfl_xor(sm, 8); sm += __shfl_xor(sm, 16); sm += __shfl_xor(sm, 32);
        float inv = 1.f/sm;
        float sv0 = e0*inv, sv1 = e1*inv;
        s2s[r*17 + k0]     = sv0;
        s2s[r*17 + k0 + 1] = sv1;
        ((u32*)(xb + (size_t)(rbase + r)*128))[kq] =
            (u32)f2bf(sv0) | ((u32)f2bf(sv1) << 16);
        float q2v = sv0*sv0 + sv1*sv1;
        q2v += __shfl_xor(q2v, 8); q2v += __shfl_xor(q2v, 16); q2v += __shfl_xor(q2v, 32);
        float denp = (kq == 0)
            ? (xb[(size_t)(rbase + r)*128 + 113]*invv + EPSF)*q2v : 0.f;
        denp += __shfl_down(denp, 1);
        denp += __shfl_down(denp, 2);
        denp += __shfl_down(denp, 4);
        if ((tid & 63) == 0) pwd[wv] = denp;
    }
    __syncthreads();
    if (tid == 0) atomicAdd(accp(xb,b,1120), pwd[0]+pwd[1]+pwd[2]+pwd[3]);
    {
        int k = tid >> 4, l = tid & 15;
        float s = 0.f;
        for (int r = 0; r < 32; ++r) s += s2s[r*17 + k]*s2s[r*17 + l];
        atomicAdd(accp(xb,b,774 + tid), s);
    }
    for (int e = tid; e < 512; e += 256) {
        int k = e >> 5, h = e & 31;
        float s = 0.f;
        for (int r = 0; r < 32; ++r) s += s2s[r*17 + k]*x2s[r*34 + h];
        atomicAdd(accp(xb,b,6 + k*32 + h), s);
    }
}

// ---------------- FALLBACK (ws < 33 MB): staged k_y + k_d2 (r5 behavior).
__global__ __launch_bounds__(256) void k_y_st(const u32* __restrict__ anb, float* xb)
{
    __shared__ __align__(16) u16 X[16*1032];
    int tid = threadIdx.x;
    int hq = blockIdx.x, ni = blockIdx.y, b = blockIdx.z;
    int w = tid >> 6, lane = tid & 63;
    int q = lane >> 4, c16 = lane & 15;
    int rloc = w*16 + c16;
    size_t rowg = (size_t)(b*1024 + ni*64 + rloc);
    u32* Xu = (u32*)X;
    for (int e = tid; e < 2048; e += 256) {
        int mp = e >> 2, h4 = e & 3;
        int m0 = mp*2;
        const float* p0 = &xb[(size_t)(b*1024 + m0)*128 + 64 + hq*16 + h4*4];
        float4 v0 = *(const float4*)p0;
        float4 v1 = *(const float4*)(p0 + 128);
        Xu[(h4*4 + 0)*516 + mp] = (u32)f2bf(v0.x) | ((u32)f2bf(v1.x) << 16);
        Xu[(h4*4 + 1)*516 + mp] = (u32)f2bf(v0.y) | ((u32)f2bf(v1.y) << 16);
        Xu[(h4*4 + 2)*516 + mp] = (u32)f2bf(v0.z) | ((u32)f2bf(v1.z) << 16);
        Xu[(h4*4 + 3)*516 + mp] = (u32)f2bf(v0.w) | ((u32)f2bf(v1.w) << 16);
    }
    __syncthreads();
    f32x4 acc = {0.f,0.f,0.f,0.f};
    #pragma unroll 8
    for (int ks = 0; ks < 32; ++ks) {
        bf16x8 af = *(const bf16x8*)&anb[rowg*512 + ks*16 + q*4];
        bf16x8 bx = *(const bf16x8*)&X[c16*1032 + ks*32 + q*8];
        acc = __builtin_amdgcn_mfma_f32_16x16x32_bf16(af, bx, acc, 0, 0, 0);
    }
    #pragma unroll
    for (int rg = 0; rg < 4; ++rg) {
        size_t orow = (size_t)(b*1024 + ni*64 + w*16 + q*4 + rg)*128;
        xb[orow + 32 + hq*16 + c16] = acc[rg];
    }
}

__global__ __launch_bounds__(256) void k_d2(float* xb,
        const float* __restrict__ Wrel1, const float* __restrict__ brel1,
        const float* __restrict__ Wroot1,
        const float* __restrict__ Wp2, const float* __restrict__ bp2)
{
    __shared__ float ys[32*34];
    __shared__ float x1n[32*34];
    __shared__ float x2s[32*34];
    __shared__ float s2s[32*17];
    __shared__ float WrT[32*33], WoT[32*33], WpT[16*33];
    __shared__ float pwd[4];
    int tid = threadIdx.x;
    int tq = blockIdx.x, b = blockIdx.y;
    int rbase = b*1024 + tq*32;
    float invv = 1.f / (*accp(xb,b,1050) + 1024.f*EPSF);
    {
        int j = tid >> 3, h0 = (tid & 7)*4;
        float4 v = *(const float4*)&Wrel1[j*32 + h0];
        WrT[(h0+0)*33 + j] = v.x;
        WrT[(h0+1)*33 + j] = v.y;
        WrT[(h0+2)*33 + j] = v.z;
        WrT[(h0+3)*33 + j] = v.w;
        float4 v2 = *(const float4*)&Wroot1[j*32 + h0];
        WoT[(h0+0)*33 + j] = v2.x;
        WoT[(h0+1)*33 + j] = v2.y;
        WoT[(h0+2)*33 + j] = v2.z;
        WoT[(h0+3)*33 + j] = v2.w;
    }
    if (tid < 128) {
        int j = tid >> 2, k0 = (tid & 3)*4;
        float4 v = *(const float4*)&Wp2[j*16 + k0];
        WpT[(k0+0)*33 + j] = v.x;
        WpT[(k0+1)*33 + j] = v.y;
        WpT[(k0+2)*33 + j] = v.z;
        WpT[(k0+3)*33 + j] = v.w;
    }
    for (int e = tid; e < 1024; e += 256) {
        int r = e >> 5, h = e & 31;
        const float* xr = xb + (size_t)(rbase + r)*128;
        ys[r*34 + h]  = xr[32 + h] * invv;
        x1n[r*34 + h] = xr[64 + h];
    }
    __syncthreads();
    {
        int h = tid & 31, tg = tid >> 5;
        float brl = brel1[h];
        const float* wr = &WrT[h*33];
        const float* wo = &WoT[h*33];
        #pragma unroll
        for (int i = 0; i < 4; ++i) {
            int r = tg + 8*i;
            float v = brl;
            for (int j = 0; j < 32; ++j)
                v += ys[r*34 + j]*wr[j] + x1n[r*34 + j]*wo[j];
            x2s[r*34 + h] = v;
        }
    }
    __syncthreads();
    {
        int rl = tid & 7, kq = (tid >> 3) & 7, wv = tid >> 6;
        int r = wv*8 + rl;
        int k0 = kq*2;
        float v0 = bp2[k0], v1 = bp2[k0 + 1];
        const float* wp0 = &WpT[k0*33];
        const float* wp1 = &WpT[(k0+1)*33];
        for (int j = 0; j < 32; ++j) {
            float xv = x2s[r*34 + j];
            v0 += xv*wp0[j];
            v1 += xv*wp1[j];
        }
        float mx = fmaxf(v0, v1);
        mx = fmaxf(mx, __shfl_xor(mx, 8));
        mx = fmaxf(mx, __shfl_xor(mx, 16));
        mx = fmaxf(mx, __shfl_xor(mx, 32));
        float e0 = expf(v0 - mx), e1 = expf(v1 - mx);
        float sm = e0 + e1;
        sm += __shfl_xor(sm, 8); sm += __shfl_xor(sm, 16); sm += __shfl_xor(sm, 32);
        float inv = 1.f/sm;
        float sv0 = e0*inv, sv1 = e1*inv;
        s2s[r*17 + k0]     = sv0;
        s2s[r*17 + k0 + 1] = sv1;
        ((u32*)(xb + (size_t)(rbase + r)*128))[kq] =
            (u32)f2bf(sv0) | ((u32)f2bf(sv1) << 16);
        float q2v = sv0*sv0 + sv1*sv1;
        q2v += __shfl_xor(q2v, 8); q2v += __shfl_xor(q2v, 16); q2v += __shfl_xor(q2v, 32);
        float denp = (kq == 0)
            ? (xb[(size_t)(rbase + r)*128 + 113]*invv + EPSF)*q2v : 0.f;
        denp += __shfl_down(denp, 1);
        denp += __shfl_down(denp, 2);
        denp += __shfl_down(denp, 4);
        if ((tid & 63) == 0) pwd[wv] = denp;
    }
    __syncthreads();
    if (tid == 0) atomicAdd(accp(xb,b,1120), pwd[0]+pwd[1]+pwd[2]+pwd[3]);
    {
        int k = tid >> 4, l = tid & 15;
        float s = 0.f;
        for (int r = 0; r < 32; ++r) s += s2s[r*17 + k]*s2s[r*17 + l];
        atomicAdd(accp(xb,b,774 + tid), s);
    }
    for (int e = tid; e < 512; e += 256) {
        int k = e >> 5, h = e & 31;
        float s = 0.f;
        for (int r = 0; r < 32; ++r) s += s2s[r*17 + k]*x2s[r*34 + h];
        atomicAdd(accp(xb,b,6 + k*32 + h), s);
    }
}

// ---------------- Kernel E (MFMA): block (miq,ni,b), 2 mi tiles, grid (8,16,16).
__global__ __launch_bounds__(256) void k_e(const u32* __restrict__ anb, float* xb)
{
    __shared__ __align__(16) u16 BufS[2][16*72];
    __shared__ __align__(16) u16 BufN[16*72];
    __shared__ __align__(16) u16 zT[16*72];
    int tid = threadIdx.x;
    int miq = blockIdx.x, ni = blockIdx.y, b = blockIdx.z;
    const u32* xu = (const u32*)xb;
    for (int e = tid; e < 512; e += 256) {
        int node = e >> 3, lw = e & 7;
        u32 pp = xu[(size_t)(b*1024 + ni*64 + node)*128 + lw];
        BufN[(lw*2)*72 + node]     = (u16)pp;
        BufN[(lw*2 + 1)*72 + node] = (u16)(pp >> 16);
    }
    for (int e = tid; e < 1024; e += 256) {
        int t = e >> 9, e2 = e & 511;
        int node = e2 >> 3, lw = e2 & 7;
        u32 pp = xu[(size_t)(b*1024 + (miq*2 + t)*64 + node)*128 + lw];
        BufS[t][(lw*2)*72 + node]     = (u16)pp;
        BufS[t][(lw*2 + 1)*72 + node] = (u16)(pp >> 16);
    }
    int w = tid >> 6, lane = tid & 63;
    int q = lane >> 4, c16 = lane & 15;
    int rloc = w*16 + c16;
    size_t arow = (size_t)(b*1024 + ni*64 + rloc)*512;
    bf16x8 ya[2][2];
    #pragma unroll
    for (int t = 0; t < 2; ++t) {
        ya[t][0] = *(const bf16x8*)&anb[arow + (miq*2 + t)*32 + q*4];
        ya[t][1] = *(const bf16x8*)&anb[arow + (miq*2 + t)*32 + 16 + q*4];
    }
    __syncthreads();
    f32x4 zacc = {0.f, 0.f, 0.f, 0.f};
    #pragma unroll
    for (int t = 0; t < 2; ++t) {
        bf16x8 yb0 = *(const bf16x8*)&BufS[t][c16*72 + q*8];
        bf16x8 yb1 = *(const bf16x8*)&BufS[t][c16*72 + 32 + q*8];
        zacc = __builtin_amdgcn_mfma_f32_16x16x32_bf16(ya[t][0], yb0, zacc, 0, 0, 0);
        zacc = __builtin_amdgcn_mfma_f32_16x16x32_bf16(ya[t][1], yb1, zacc, 0, 0, 0);
    }
    #pragma unroll
    for (int rg = 0; rg < 4; ++rg)
        zT[c16*72 + w*16 + q*4 + rg] = f2bf(zacc[rg]);
    __syncthreads();
    if (w == 0) {
        bf16x8 af0 = *(const bf16x8*)&BufN[c16*72 + q*8];
        bf16x8 af1 = *(const bf16x8*)&BufN[c16*72 + 32 + q*8];
        bf16x8 bz0 = *(const bf16x8*)&zT[c16*72 + q*8];
        bf16x8 bz1 = *(const bf16x8*)&zT[c16*72 + 32 + q*8];
        f32x4 oamv = {0.f, 0.f, 0.f, 0.f};
        oamv = __builtin_amdgcn_mfma_f32_16x16x32_bf16(af0, bz0, oamv, 0, 0, 0);
        oamv = __builtin_amdgcn_mfma_f32_16x16x32_bf16(af1, bz1, oamv, 0, 0, 0);
        #pragma unroll
        for (int rg = 0; rg < 4; ++rg)
            atomicAdd(accp(xb, b, 518 + (q*4 + rg)*16 + c16), oamv[rg]);
    }
}

// ---------------- Kernel F1: per-batch finalize (grid 16) + last-block scalar fold.
__global__ __launch_bounds__(256) void k_f1(float* xb,
        const float* __restrict__ Wrel2, const float* __restrict__ brel2,
        const float* __restrict__ Wroot2,
        const float* __restrict__ W_lin2, const float* __restrict__ b_lin2,
        const float* __restrict__ W_lin3, const float* __restrict__ b_lin3,
        float* __restrict__ outp)
{
    __shared__ float oam_s[256], ssm_s[256], outm_s[512];
    __shared__ float dks[16], csoa[16];
    __shared__ float cs0[32], cs1[32], xsum[32], x5[32], lgs[10];
    __shared__ float red[4];
    __shared__ int isLast;
    int b = blockIdx.x;
    int tid = threadIdx.x;
    float invv = 1.f / (*accp(xb,b,1050) + 1024.f*EPSF);
    oam_s[tid] = *accp(xb,b,518 + tid) * invv;
    ssm_s[tid] = *accp(xb,b,774 + tid);
    for (int e = tid; e < 512; e += 256) outm_s[e] = *accp(xb,b,6 + e);
    __syncthreads();
    if (tid < 16) {
        float rsv = 0.f;
        for (int l = 0; l < 16; ++l) if (l != tid) rsv += oam_s[tid*16 + l];
        dks[tid] = sqrtf(fmaxf(rsv, 0.f) + EPSF) + EPSF;
    }
    {
        float v = ssm_s[tid];
        float p = v*v;
        for (int off = 32; off; off >>= 1) p += __shfl_down(p, off);
        if ((tid & 63) == 0) red[tid >> 6] = p;
    }
    __syncthreads();
    if (tid < 16) {
        float s = 0.f;
        for (int k2 = 0; k2 < 16; ++k2)
            if (k2 != tid) s += oam_s[k2*16 + tid] / dks[k2];
        csoa[tid] = s / dks[tid];
    }
    if (tid < 32) {
        float s0 = 0.f, s1 = 0.f;
        for (int l = 0; l < 16; ++l) {
            float ov = outm_s[l*32 + tid];
            s0 += ov;
            s1 += csoa[l] * ov;   // same wave as csoa writers; intra-wave order holds
        }
        cs0[tid] = s0; cs1[tid] = s1;
    }
    if (tid == 64) {
        float T1v  = *accp(xb,b,1064);
        float Pgv  = *accp(xb,b,1092);
        float Q2v  = *accp(xb,b,1106);
        float Tq1v = *accp(xb,b,1078);
        float T2v  = *accp(xb,b,1120);
        float tr2 = 0.f, trs = 0.f;
        for (int k2 = 0; k2 < 16; ++k2) { tr2 += oam_s[k2*17]; trs += ssm_s[k2*17]; }
        float fr2 = red[0] + red[1] + red[2] + red[3];
        __hip_atomic_store(accp(xb,b,1030), (T1v - Pgv) / (T1v + EPSF),
                           __ATOMIC_RELAXED, __HIP_MEMORY_SCOPE_AGENT);
        __hip_atomic_store(accp(xb,b,1031), 65.f - 2.f*Tq1v/sqrtf(fmaxf(Q2v, 1e-30f)),
                           __ATOMIC_RELAXED, __HIP_MEMORY_SCOPE_AGENT);
        __hip_atomic_store(accp(xb,b,1032), -tr2 / T2v,
                           __ATOMIC_RELAXED, __HIP_MEMORY_SCOPE_AGENT);
        __hip_atomic_store(accp(xb,b,1033),
                           sqrtf(fmaxf(2.f - trs/(2.f*sqrtf(fmaxf(fr2, 1e-30f))), 0.f)),
                           __ATOMIC_RELAXED, __HIP_MEMORY_SCOPE_AGENT);
    }
    __syncthreads();
    if (tid < 32) {
        float v = 16.f * brel2[tid];
        for (int j = 0; j < 32; ++j)
            v += cs1[j]*Wrel2[j*32 + tid] + cs0[j]*Wroot2[j*32 + tid];
        xsum[tid] = v;
    }
    __syncthreads();
    if (tid < 32) {
        float v = b_lin2[tid];
        for (int j = 0; j < 32; ++j) v += xsum[j]*W_lin2[j*32 + tid];
        x5[tid] = fmaxf(v, 0.f);
    }
    __syncthreads();
    if (tid < 10) {
        float v = b_lin3[tid];
        for (int j = 0; j < 32; ++j) v += x5[j]*W_lin3[j*10 + tid];
        lgs[tid] = v;
    }
    __syncthreads();
    if (tid < 10) {
        float mx = -1e30f;
        for (int t = 0; t < 10; ++t) mx = fmaxf(mx, lgs[t]);
        float sum = 0.f;
        for (int t = 0; t < 10; ++t) sum += expf(lgs[t] - mx);
        outp[b*10 + tid] = lgs[tid] - mx - logf(sum);
    }
    __syncthreads();
    if (tid == 0) {
        __threadfence();
        float old = atomicAdd(accp(xb,0,1035), 1.f);
        isLast = (old > 14.5f) ? 1 : 0;
    }
    __syncthreads();
    if (isLast && tid < 64) {
        __threadfence();
        int b2 = tid & 15, which = tid >> 4;
        float v = __hip_atomic_load(accp(xb,b2,1030 + which),
                                    __ATOMIC_RELAXED, __HIP_MEMORY_SCOPE_AGENT);
        for (int off = 1; off < 16; off <<= 1) v += __shfl_xor(v, off);
        float ct = __shfl(v, 0);
        float o1 = __shfl(v, 16);
        float mc = __shfl(v, 32);
        float o2 = __shfl(v, 48);
        if (tid == 0) {
            outp[160] = ct/16.f + sqrtf(fmaxf(o1, 0.f));
            outp[161] = mc/16.f + o2/16.f;
        }
    }
}

extern "C" void kernel_launch(void* const* d_in, const int* in_sizes, int n_in,
                              void* d_out, int out_size, void* d_ws, size_t ws_size,
                              hipStream_t stream)
{
    float* xb        = (float*)d_in[0];   // x, reused as scratch (restored by harness)
    const float* adj = (const float*)d_in[1];   // READ-ONLY
    const float* W_lin1 = (const float*)d_in[3];
    const float* b_lin1 = (const float*)d_in[4];
    const float* W_pool1= (const float*)d_in[5];
    const float* b_pool1= (const float*)d_in[6];
    const float* W_pool2= (const float*)d_in[7];
    const float* b_pool2= (const float*)d_in[8];
    const float* Wrel1  = (const float*)d_in[9];
    const float* brel1  = (const float*)d_in[10];
    const float* Wroot1 = (const float*)d_in[11];
    const float* Wrel2  = (const float*)d_in[12];
    const float* brel2  = (const float*)d_in[13];
    const float* Wroot2 = (const float*)d_in[14];
    const float* W_lin2 = (const float*)d_in[15];
    const float* b_lin2 = (const float*)d_in[16];
    const float* W_lin3 = (const float*)d_in[17];
    const float* b_lin3 = (const float*)d_in[18];
    u32* anb = (u32*)d_ws;   // 32 MB, fully overwritten by k_c
    bool hasX = ws_size >= (((size_t)33) << 20);
    u32* x1t = hasX ? anb + (size_t)8*1024*1024 : (u32*)nullptr;  // +32 MB, 1 MB
    (void)in_sizes; (void)n_in; (void)out_size;

    k_a<<<dim3(1024),      dim3(256), 0, stream>>>(xb, W_lin1, b_lin1, W_pool1, b_pool1,
                                                   x1t);
    k_c<<<dim3(8,16,16),   dim3(256), 0, stream>>>(adj, xb, anb);
    if (hasX) {
        k_yd<<<dim3(32,16), dim3(256), 0, stream>>>(anb, x1t, xb, Wrel1, brel1, Wroot1,
                                                    W_pool2, b_pool2);
    } else {
        k_y_st<<<dim3(2,16,16), dim3(256), 0, stream>>>(anb, xb);
        k_d2<<<dim3(32,16),     dim3(256), 0, stream>>>(xb, Wrel1, brel1, Wroot1,
                                                        W_pool2, b_pool2);
    }
    k_e<<<dim3(8,16,16),   dim3(256), 0, stream>>>(anb, xb);
    k_f1<<<dim3(16),       dim3(256), 0, stream>>>(xb, Wrel2, brel2, Wroot2,
                                                   W_lin2, b_lin2, W_lin3, b_lin3,
                                                   (float*)d_out);
}

// Round 9
// 218.292 us; speedup vs baseline: 1.0384x; 1.0136x over previous
//
#include <hip/hip_runtime.h>

typedef unsigned short u16;
typedef unsigned int   u32;
typedef __attribute__((ext_vector_type(8))) short bf16x8;
typedef __attribute__((ext_vector_type(4))) float f32x4;

#define EPSF 1e-15f

// Per-row layout inside the x input buffer (f32, row stride 128 floats = 512 B):
//   [0,32)   st as bf16 (64 values packed into 32 u32 words) [k_a; read by k_c]
//            -> after k_yd, [0,8) REUSED for s2 packed bf16 [read by k_e]
//   [32,48)  x1T bf16 region: element (h,m) of batch b lives at row
//            b*1024 + h*32 + (m>>5), float 32 + ((m&31)>>1)  [k_a -> k_yd]
//            (was the fallback y slot; fallback path deleted in r9 — the
//            ws_size>=33MB gate was almost certainly never true, so the
//            fused k_yd had never actually run before this round)
//   [64,96)  x1
//   112      q1 = ||st_row||^2 (bf16-rounded st)
//   113      d2 = rowsum(adjn_unscaled)
//   [114,128) spare -> batch accumulators, rows b*1024 + a/14
// Accumulator slots (a): 6..518 outm (k*32+h), 518..774 oam UNSCALED,
//   774..1030 ssm, 1030..1033 loss scalars, 1035 k_f1 counter.
//   Batch scalars in DISTINCT cache lines (r6 lesson: shared line -> +7 µs):
//   1050 Dsum, 1064 T1, 1078 Tq1, 1092 Pg, 1106 Q2, 1120 T2.
// d_ws: anb only (packed bf16 an, [b][n][m/2] u32, exactly 32 MB).
__device__ __forceinline__ float* accp(float* xb, int b, int a) {
    return xb + (size_t)(b*1024 + a/14)*128 + 114 + (a % 14);
}

__device__ __forceinline__ float bf2f(u16 u) {
    union { u32 i; float f; } v; v.i = ((u32)u) << 16; return v.f;
}
__device__ __forceinline__ u16 f2bf(float f) {
    union { u32 i; float f; } v; v.f = f;
    u32 r = v.i + 0x7fffu + ((v.i >> 16) & 1u);
    return (u16)(r >> 16);
}

// ---------------- Kernel A: x1 = x@W1+b1 ; st = tanh(x1@Wp1+bp1) stored bf16;
// q1 = ||st_bf16||^2 ; zero d2 + accumulator spares; x1T bf16 into row-spare.
__global__ __launch_bounds__(256) void k_a(float* xb,
        const float* __restrict__ W1, const float* __restrict__ b1,
        const float* __restrict__ Wp1, const float* __restrict__ bp1)
{
    __shared__ float W1sT[32*133];   // [col][f]
    __shared__ float Wp1sT[64*33];   // [l][h]
    __shared__ float xs[16][128];
    __shared__ float x1s[16][32];
    int tid = threadIdx.x;
    for (int i = tid; i < 1024; i += 256) {
        int f = i >> 3, c0 = (i & 7)*4;
        float4 v = *(const float4*)&W1[f*32 + c0];
        W1sT[(c0+0)*133 + f] = v.x;
        W1sT[(c0+1)*133 + f] = v.y;
        W1sT[(c0+2)*133 + f] = v.z;
        W1sT[(c0+3)*133 + f] = v.w;
    }
    for (int i = tid; i < 512; i += 256) {
        int h = i >> 4, l0 = (i & 15)*4;
        float4 v = *(const float4*)&Wp1[h*64 + l0];
        Wp1sT[(l0+0)*33 + h] = v.x;
        Wp1sT[(l0+1)*33 + h] = v.y;
        Wp1sT[(l0+2)*33 + h] = v.z;
        Wp1sT[(l0+3)*33 + h] = v.w;
    }
    int rbase = blockIdx.x*16;
    for (int e = tid; e < 512; e += 256) {
        int rr = e >> 5, c = e & 31;
        *(float4*)&xs[rr][c*4] = *(const float4*)&xb[(size_t)(rbase + rr)*128 + c*4];
    }
    __syncthreads();
    int w = tid >> 6, l = tid & 63;
    int col = l & 31, half = l >> 5;
    #pragma unroll
    for (int i = 0; i < 4; ++i) {
        int rr = w*4 + i;
        float* xr = xb + (size_t)(rbase + rr)*128;
        if (l < 15) xr[113 + l] = 0.f;
        float acc = half ? 0.f : b1[col];
        const float* xrow = &xs[rr][half*64];
        const float* wrow = &W1sT[col*133 + half*64];
        for (int f = 0; f < 64; ++f) acc += xrow[f]*wrow[f];
        acc += __shfl_down(acc, 32);
        if (l < 32) x1s[rr][l] = acc;
    }
    __syncthreads();
    // x1T bf16 write into row-spare [32,48): thread h=tid<32 packs its block's
    // 16 m-values (32 B) -> row b*1024 + h*32 + (mbase>>5), float 32 or 40.
    // Race-free: distinct (h, mbase) -> distinct 32B halves of distinct rows.
    if (tid < 32) {
        int b = rbase >> 10, mbase = rbase & 1023;
        u32 pk[8];
        #pragma unroll
        for (int i2 = 0; i2 < 8; ++i2)
            pk[i2] = (u32)f2bf(x1s[2*i2][tid]) | ((u32)f2bf(x1s[2*i2+1][tid]) << 16);
        float* dst = xb + (size_t)(b*1024 + tid*32 + (mbase >> 5))*128 + 32
                        + ((mbase & 31) >> 1);
        *(uint4*)dst       = make_uint4(pk[0], pk[1], pk[2], pk[3]);
        *(uint4*)(dst + 4) = make_uint4(pk[4], pk[5], pk[6], pk[7]);
    }
    #pragma unroll
    for (int i = 0; i < 4; ++i) {
        int rr = w*4 + i;
        float* xr = xb + (size_t)(rbase + rr)*128;
        if (l < 32) xr[64 + l] = x1s[rr][l];
        float acc = bp1[l];
        const float* wp = &Wp1sT[l*33];
        for (int h = 0; h < 32; ++h) acc += x1s[rr][h]*wp[h];
        float sv = tanhf(acc);
        u32 me = (u32)f2bf(sv);
        u32 nb = __shfl_down(me, 1);
        if (!(l & 1)) ((u32*)xr)[l >> 1] = me | (nb << 16);
        float svr = bf2f((u16)me);
        float qv = svr*svr;
        for (int off = 32; off; off >>= 1) qv += __shfl_down(qv, off);
        if (l == 0) xr[112] = qv;
    }
}

// ---------------- Kernel C (MFMA): r2/r5 configuration (measured best 42-44 µs).
// TWO tj tiles per block, grid (8,16,16), BufA staged, bounds(256,5).
// r3 (direct-A + 6/CU) = 55 µs write amplification; r4 (1-tile LDS store) = 66 µs
// lost MLP; r6 (batch scalars on one line) = 49 µs atomic serialization.
// r9: f2bf packs -> v_cvt_pk_bf16_f32 (RNE, bit-identical; ~10x fewer VALU ops
// on the store path of a 30%-VALUBusy kernel).
__global__ __launch_bounds__(256, 5) void k_c(const float* __restrict__ adj, float* xb,
                                              u32* __restrict__ anb)
{
    __shared__ __align__(16) u16 BufA[64*72];     // st_ti
    __shared__ __align__(16) u16 BufB[2][64*72];  // st_tj (2 tiles)
    __shared__ __align__(16) float qAs[64], qBs[2][64];
    __shared__ float pw[5][4];
    int tid = threadIdx.x;
    int tjq = blockIdx.x, ti = blockIdx.y, b = blockIdx.z;
    int w = tid >> 6, lane = tid & 63;
    int q = lane >> 4, c16 = lane & 15;
    int rloc = w*16 + c16;
    size_t rowg = (size_t)(b*1024 + ti*64 + rloc);
    float4 a4s[2][4];
    #pragma unroll
    for (int tt = 0; tt < 2; ++tt)
        #pragma unroll
        for (int t = 0; t < 4; ++t)
            a4s[tt][t] = *(const float4*)&adj[rowg*1024 + (tjq*2 + tt)*64 + t*16 + q*4];
    const u32* xu = (const u32*)xb;
    for (int e = tid; e < 512; e += 256) {
        int n = e >> 3, c = e & 7;
        *(float4*)&BufA[n*72 + c*8] = *(const float4*)&xu[(size_t)(b*1024 + ti*64 + n)*128 + c*4];
    }
    for (int e = tid; e < 1024; e += 256) {
        int n2 = e >> 3, c = e & 7;
        int tt = n2 >> 6, n = n2 & 63;
        *(float4*)&BufB[tt][n*72 + c*8] =
            *(const float4*)&xu[(size_t)(b*1024 + (tjq*2 + tt)*64 + n)*128 + c*4];
    }
    if (tid < 64) qAs[tid] = xb[(size_t)(b*1024 + ti*64 + tid)*128 + 112];
    else if (tid < 192) {
        int t2 = tid - 64;
        qBs[t2 >> 6][t2 & 63] =
            xb[(size_t)(b*1024 + (tjq*2 + (t2 >> 6))*64 + (t2 & 63))*128 + 112];
    }
    __syncthreads();
    bf16x8 bfr0 = *(const bf16x8*)&BufA[rloc*72 + q*8];
    bf16x8 bfr1 = *(const bf16x8*)&BufA[rloc*72 + 32 + q*8];
    float qa = qAs[rloc];
    float dsum = 0.f, rsum = 0.f, Pt = 0.f, Qt = 0.f;
    #pragma unroll
    for (int tt = 0; tt < 2; ++tt) {
        f32x4 g[4];
        #pragma unroll
        for (int t = 0; t < 4; ++t) {
            bf16x8 af0 = *(const bf16x8*)&BufB[tt][(t*16 + c16)*72 + q*8];
            bf16x8 af1 = *(const bf16x8*)&BufB[tt][(t*16 + c16)*72 + 32 + q*8];
            f32x4 gg = {0.f, 0.f, 0.f, 0.f};
            gg = __builtin_amdgcn_mfma_f32_16x16x32_bf16(af0, bfr0, gg, 0, 0, 0);
            gg = __builtin_amdgcn_mfma_f32_16x16x32_bf16(af1, bfr1, gg, 0, 0, 0);
            g[t] = gg;
        }
        #pragma unroll
        for (int t = 0; t < 4; ++t) {
            float4 a4 = a4s[tt][t];
            float4 qb4 = *(const float4*)&qBs[tt][t*16 + q*4];
            float av[4] = {a4.x, a4.y, a4.z, a4.w};
            float qb[4] = {qb4.x, qb4.y, qb4.z, qb4.w};
            float o[4];
            #pragma unroll
            for (int rg = 0; rg < 4; ++rg) {
                float d2v = qa + qb[rg] - 2.f*g[t][rg];
                float dist = sqrtf(fmaxf(d2v, 0.f));
                o[rg] = dist * av[rg];
                dsum += av[rg];
                rsum += o[rg];
                Pt += av[rg]*g[t][rg];
                Qt += g[t][rg]*g[t][rg];
            }
            u32 p0, p1;
            asm("v_cvt_pk_bf16_f32 %0, %1, %2" : "=v"(p0) : "v"(o[0]), "v"(o[1]));
            asm("v_cvt_pk_bf16_f32 %0, %1, %2" : "=v"(p1) : "v"(o[2]), "v"(o[3]));
            *(uint2*)&anb[rowg*512 + (tjq*2 + tt)*32 + t*8 + q*2] = make_uint2(p0, p1);
        }
    }
    rsum += __shfl_xor(rsum, 16); rsum += __shfl_xor(rsum, 32);
    dsum += __shfl_xor(dsum, 16); dsum += __shfl_xor(dsum, 32);
    if (q == 0) atomicAdd(&xb[rowg*128 + 113], rsum);
    float cd = (q == 0) ? dsum : 0.f;
    float c1 = (q == 0) ? qa*dsum : 0.f;
    float cq = (q == 0 && tjq == 0) ? qa : 0.f;
    for (int off = 32; off; off >>= 1) {
        Pt += __shfl_down(Pt, off); Qt += __shfl_down(Qt, off);
        cd += __shfl_down(cd, off); c1 += __shfl_down(c1, off); cq += __shfl_down(cq, off);
    }
    if (lane == 0) { pw[0][w]=Pt; pw[1][w]=Qt; pw[2][w]=cd; pw[3][w]=c1; pw[4][w]=cq; }
    __syncthreads();
    if (tid == 0) {
        atomicAdd(accp(xb,b,1092), pw[0][0]+pw[0][1]+pw[0][2]+pw[0][3]);  // Pg
        atomicAdd(accp(xb,b,1106), pw[1][0]+pw[1][1]+pw[1][2]+pw[1][3]);  // Q2
        atomicAdd(accp(xb,b,1050), pw[2][0]+pw[2][1]+pw[2][2]+pw[2][3]);  // Dsum
        atomicAdd(accp(xb,b,1064), pw[3][0]+pw[3][1]+pw[3][2]+pw[3][3]);  // T1
        if (tjq == 0)
            atomicAdd(accp(xb,b,1078), pw[4][0]+pw[4][1]+pw[4][2]+pw[4][3]);  // Tq1
    }
}

// ---------------- Kernel YD (fused y + d2): 32 rows/block, grid (32,16).
// Phase 1: y = an@x1 via 2x2 wave tiling, direct loads (anb own rows; x1T from
// the xb row-spare region, L2/L3-resident); ys = y*invv straight to LDS —
// y never touches HBM. Phase 2: x2 GEMM + softmax s2 + outm/ssm/T2.
__global__ __launch_bounds__(256) void k_yd(const u32* __restrict__ anb, float* xb,
        const float* __restrict__ Wrel1, const float* __restrict__ brel1,
        const float* __restrict__ Wroot1,
        const float* __restrict__ Wp2, const float* __restrict__ bp2)
{
    __shared__ float ys[32*33];
    __shared__ float x1n[32*34];
    __shared__ float x2s[32*34];
    __shared__ float s2s[32*17];
    __shared__ float WrT[32*33], WoT[32*33], WpT[16*33];
    __shared__ float pwd[4];
    int tid = threadIdx.x;
    int tq = blockIdx.x, b = blockIdx.y;
    int rbase = b*1024 + tq*32;
    float invv = 1.f / (*accp(xb,b,1050) + 1024.f*EPSF);
    {
        int j = tid >> 3, h0 = (tid & 7)*4;
        float4 v = *(const float4*)&Wrel1[j*32 + h0];
        WrT[(h0+0)*33 + j] = v.x;
        WrT[(h0+1)*33 + j] = v.y;
        WrT[(h0+2)*33 + j] = v.z;
        WrT[(h0+3)*33 + j] = v.w;
        float4 v2 = *(const float4*)&Wroot1[j*32 + h0];
        WoT[(h0+0)*33 + j] = v2.x;
        WoT[(h0+1)*33 + j] = v2.y;
        WoT[(h0+2)*33 + j] = v2.z;
        WoT[(h0+3)*33 + j] = v2.w;
    }
    if (tid < 128) {
        int j = tid >> 2, k0 = (tid & 3)*4;
        float4 v = *(const float4*)&Wp2[j*16 + k0];
        WpT[(k0+0)*33 + j] = v.x;
        WpT[(k0+1)*33 + j] = v.y;
        WpT[(k0+2)*33 + j] = v.z;
        WpT[(k0+3)*33 + j] = v.w;
    }
    {
        int r = tid >> 3, c = tid & 7;
        *(float4*)&x1n[r*34 + c*4] = *(const float4*)&xb[(size_t)(rbase + r)*128 + 64 + c*4];
    }
    // ---- phase 1: y MFMA, no barriers in K-loop
    int w = tid >> 6, lane = tid & 63;
    int q = lane >> 4, c16 = lane & 15;
    int rh = w & 1, hh = w >> 1;
    int h = hh*16 + c16;
    size_t rowg = (size_t)(rbase + rh*16 + c16);
    // x1T fragment (h, m=ks*32+q*8 ..+8): row b*1024 + h*32 + ks, float 32+q*4
    const float* xtb = xb + (size_t)(b*1024 + h*32)*128 + 32 + q*4;
    f32x4 acc = {0.f,0.f,0.f,0.f};
    #pragma unroll 8
    for (int ks = 0; ks < 32; ++ks) {
        bf16x8 af = *(const bf16x8*)&anb[rowg*512 + ks*16 + q*4];
        bf16x8 bx = *(const bf16x8*)&xtb[(size_t)ks*128];
        acc = __builtin_amdgcn_mfma_f32_16x16x32_bf16(af, bx, acc, 0, 0, 0);
    }
    #pragma unroll
    for (int rg = 0; rg < 4; ++rg)
        ys[(rh*16 + q*4 + rg)*33 + hh*16 + c16] = acc[rg]*invv;
    __syncthreads();
    // ---- phase 2a: x2 GEMM
    {
        int hc = tid & 31, tg = tid >> 5;
        float brl = brel1[hc];
        const float* wr = &WrT[hc*33];
        const float* wo = &WoT[hc*33];
        #pragma unroll
        for (int i = 0; i < 4; ++i) {
            int r = tg + 8*i;
            float v = brl;
            for (int j = 0; j < 32; ++j)
                v += ys[r*33 + j]*wr[j] + x1n[r*34 + j]*wo[j];
            x2s[r*34 + hc] = v;
        }
    }
    __syncthreads();
    // ---- phase 2b: softmax s2, pack bf16 to xb[0,8)
    {
        int rl = tid & 7, kq = (tid >> 3) & 7, wv = tid >> 6;
        int r = wv*8 + rl;
        int k0 = kq*2;
        float v0 = bp2[k0], v1 = bp2[k0 + 1];
        const float* wp0 = &WpT[k0*33];
        const float* wp1 = &WpT[(k0+1)*33];
        for (int j = 0; j < 32; ++j) {
            float xv = x2s[r*34 + j];
            v0 += xv*wp0[j];
            v1 += xv*wp1[j];
        }
        float mx = fmaxf(v0, v1);
        mx = fmaxf(mx, __shfl_xor(mx, 8));
        mx = fmaxf(mx, __shfl_xor(mx, 16));
        mx = fmaxf(mx, __shfl_xor(mx, 32));
        float e0 = expf(v0 - mx), e1 = expf(v1 - mx);
        float sm = e0 + e1;
        sm += __shfl_xor(sm, 8); sm += __shfl_xor(sm, 16); sm += __shfl_xor(sm, 32);
        float inv = 1.f/sm;
        float sv0 = e0*inv, sv1 = e1*inv;
        s2s[r*17 + k0]     = sv0;
        s2s[r*17 + k0 + 1] = sv1;
        ((u32*)(xb + (size_t)(rbase + r)*128))[kq] =
            (u32)f2bf(sv0) | ((u32)f2bf(sv1) << 16);
        float q2v = sv0*sv0 + sv1*sv1;
        q2v += __shfl_xor(q2v, 8); q2v += __shfl_xor(q2v, 16); q2v += __shfl_xor(q2v, 32);
        float denp = (kq == 0)
            ? (xb[(size_t)(rbase + r)*128 + 113]*invv + EPSF)*q2v : 0.f;
        denp += __shfl_down(denp, 1);
        denp += __shfl_down(denp, 2);
        denp += __shfl_down(denp, 4);
        if ((tid & 63) == 0) pwd[wv] = denp;
    }
    __syncthreads();
    if (tid == 0) atomicAdd(accp(xb,b,1120), pwd[0]+pwd[1]+pwd[2]+pwd[3]);
    {
        int k = tid >> 4, l = tid & 15;
        float s = 0.f;
        for (int r = 0; r < 32; ++r) s += s2s[r*17 + k]*s2s[r*17 + l];
        atomicAdd(accp(xb,b,774 + tid), s);
    }
    for (int e = tid; e < 512; e += 256) {
        int k = e >> 5, hc = e & 31;
        float s = 0.f;
        for (int r = 0; r < 32; ++r) s += s2s[r*17 + k]*x2s[r*34 + hc];
        atomicAdd(accp(xb,b,6 + k*32 + hc), s);
    }
}

// ---------------- Kernel E (MFMA): block (miq,ni,b), 2 mi tiles, grid (8,16,16).
__global__ __launch_bounds__(256) void k_e(const u32* __restrict__ anb, float* xb)
{
    __shared__ __align__(16) u16 BufS[2][16*72];
    __shared__ __align__(16) u16 BufN[16*72];
    __shared__ __align__(16) u16 zT[16*72];
    int tid = threadIdx.x;
    int miq = blockIdx.x, ni = blockIdx.y, b = blockIdx.z;
    const u32* xu = (const u32*)xb;
    for (int e = tid; e < 512; e += 256) {
        int node = e >> 3, lw = e & 7;
        u32 pp = xu[(size_t)(b*1024 + ni*64 + node)*128 + lw];
        BufN[(lw*2)*72 + node]     = (u16)pp;
        BufN[(lw*2 + 1)*72 + node] = (u16)(pp >> 16);
    }
    for (int e = tid; e < 1024; e += 256) {
        int t = e >> 9, e2 = e & 511;
        int node = e2 >> 3, lw = e2 & 7;
        u32 pp = xu[(size_t)(b*1024 + (miq*2 + t)*64 + node)*128 + lw];
        BufS[t][(lw*2)*72 + node]     = (u16)pp;
        BufS[t][(lw*2 + 1)*72 + node] = (u16)(pp >> 16);
    }
    int w = tid >> 6, lane = tid & 63;
    int q = lane >> 4, c16 = lane & 15;
    int rloc = w*16 + c16;
    size_t arow = (size_t)(b*1024 + ni*64 + rloc)*512;
    bf16x8 ya[2][2];
    #pragma unroll
    for (int t = 0; t < 2; ++t) {
        ya[t][0] = *(const bf16x8*)&anb[arow + (miq*2 + t)*32 + q*4];
        ya[t][1] = *(const bf16x8*)&anb[arow + (miq*2 + t)*32 + 16 + q*4];
    }
    __syncthreads();
    f32x4 zacc = {0.f, 0.f, 0.f, 0.f};
    #pragma unroll
    for (int t = 0; t < 2; ++t) {
        bf16x8 yb0 = *(const bf16x8*)&BufS[t][c16*72 + q*8];
        bf16x8 yb1 = *(const bf16x8*)&BufS[t][c16*72 + 32 + q*8];
        zacc = __builtin_amdgcn_mfma_f32_16x16x32_bf16(ya[t][0], yb0, zacc, 0, 0, 0);
        zacc = __builtin_amdgcn_mfma_f32_16x16x32_bf16(ya[t][1], yb1, zacc, 0, 0, 0);
    }
    #pragma unroll
    for (int rg = 0; rg < 4; ++rg)
        zT[c16*72 + w*16 + q*4 + rg] = f2bf(zacc[rg]);
    __syncthreads();
    if (w == 0) {
        bf16x8 af0 = *(const bf16x8*)&BufN[c16*72 + q*8];
        bf16x8 af1 = *(const bf16x8*)&BufN[c16*72 + 32 + q*8];
        bf16x8 bz0 = *(const bf16x8*)&zT[c16*72 + q*8];
        bf16x8 bz1 = *(const bf16x8*)&zT[c16*72 + 32 + q*8];
        f32x4 oamv = {0.f, 0.f, 0.f, 0.f};
        oamv = __builtin_amdgcn_mfma_f32_16x16x32_bf16(af0, bz0, oamv, 0, 0, 0);
        oamv = __builtin_amdgcn_mfma_f32_16x16x32_bf16(af1, bz1, oamv, 0, 0, 0);
        #pragma unroll
        for (int rg = 0; rg < 4; ++rg)
            atomicAdd(accp(xb, b, 518 + (q*4 + rg)*16 + c16), oamv[rg]);
    }
}

// ---------------- Kernel F1: per-batch finalize (grid 16) + last-block scalar fold.
__global__ __launch_bounds__(256) void k_f1(float* xb,
        const float* __restrict__ Wrel2, const float* __restrict__ brel2,
        const float* __restrict__ Wroot2,
        const float* __restrict__ W_lin2, const float* __restrict__ b_lin2,
        const float* __restrict__ W_lin3, const float* __restrict__ b_lin3,
        float* __restrict__ outp)
{
    __shared__ float oam_s[256], ssm_s[256], outm_s[512];
    __shared__ float dks[16], csoa[16];
    __shared__ float cs0[32], cs1[32], xsum[32], x5[32], lgs[10];
    __shared__ float red[4];
    __shared__ int isLast;
    int b = blockIdx.x;
    int tid = threadIdx.x;
    float invv = 1.f / (*accp(xb,b,1050) + 1024.f*EPSF);
    oam_s[tid] = *accp(xb,b,518 + tid) * invv;
    ssm_s[tid] = *accp(xb,b,774 + tid);
    for (int e = tid; e < 512; e += 256) outm_s[e] = *accp(xb,b,6 + e);
    __syncthreads();
    if (tid < 16) {
        float rsv = 0.f;
        for (int l = 0; l < 16; ++l) if (l != tid) rsv += oam_s[tid*16 + l];
        dks[tid] = sqrtf(fmaxf(rsv, 0.f) + EPSF) + EPSF;
    }
    {
        float v = ssm_s[tid];
        float p = v*v;
        for (int off = 32; off; off >>= 1) p += __shfl_down(p, off);
        if ((tid & 63) == 0) red[tid >> 6] = p;
    }
    __syncthreads();
    if (tid < 16) {
        float s = 0.f;
        for (int k2 = 0; k2 < 16; ++k2)
            if (k2 != tid) s += oam_s[k2*16 + tid] / dks[k2];
        csoa[tid] = s / dks[tid];
    }
    if (tid < 32) {
        float s0 = 0.f, s1 = 0.f;
        for (int l = 0; l < 16; ++l) {
            float ov = outm_s[l*32 + tid];
            s0 += ov;
            s1 += csoa[l] * ov;   // same wave as csoa writers; intra-wave order holds
        }
        cs0[tid] = s0; cs1[tid] = s1;
    }
    if (tid == 64) {
        float T1v  = *accp(xb,b,1064);
        float Pgv  = *accp(xb,b,1092);
        float Q2v  = *accp(xb,b,1106);
        float Tq1v = *accp(xb,b,1078);
        float T2v  = *accp(xb,b,1120);
        float tr2 = 0.f, trs = 0.f;
        for (int k2 = 0; k2 < 16; ++k2) { tr2 += oam_s[k2*17]; trs += ssm_s[k2*17]; }
        float fr2 = red[0] + red[1] + red[2] + red[3];
        __hip_atomic_store(accp(xb,b,1030), (T1v - Pgv) / (T1v + EPSF),
                           __ATOMIC_RELAXED, __HIP_MEMORY_SCOPE_AGENT);
        __hip_atomic_store(accp(xb,b,1031), 65.f - 2.f*Tq1v/sqrtf(fmaxf(Q2v, 1e-30f)),
                           __ATOMIC_RELAXED, __HIP_MEMORY_SCOPE_AGENT);
        __hip_atomic_store(accp(xb,b,1032), -tr2 / T2v,
                           __ATOMIC_RELAXED, __HIP_MEMORY_SCOPE_AGENT);
        __hip_atomic_store(accp(xb,b,1033),
                           sqrtf(fmaxf(2.f - trs/(2.f*sqrtf(fmaxf(fr2, 1e-30f))), 0.f)),
                           __ATOMIC_RELAXED, __HIP_MEMORY_SCOPE_AGENT);
    }
    __syncthreads();
    if (tid < 32) {
        float v = 16.f * brel2[tid];
        for (int j = 0; j < 32; ++j)
            v += cs1[j]*Wrel2[j*32 + tid] + cs0[j]*Wroot2[j*32 + tid];
        xsum[tid] = v;
    }
    __syncthreads();
    if (tid < 32) {
        float v = b_lin2[tid];
        for (int j = 0; j < 32; ++j) v += xsum[j]*W_lin2[j*32 + tid];
        x5[tid] = fmaxf(v, 0.f);
    }
    __syncthreads();
    if (tid < 10) {
        float v = b_lin3[tid];
        for (int j = 0; j < 32; ++j) v += x5[j]*W_lin3[j*10 + tid];
        lgs[tid] = v;
    }
    __syncthreads();
    if (tid < 10) {
        float mx = -1e30f;
        for (int t = 0; t < 10; ++t) mx = fmaxf(mx, lgs[t]);
        float sum = 0.f;
        for (int t = 0; t < 10; ++t) sum += expf(lgs[t] - mx);
        outp[b*10 + tid] = lgs[tid] - mx - logf(sum);
    }
    __syncthreads();
    if (tid == 0) {
        __threadfence();
        float old = atomicAdd(accp(xb,0,1035), 1.f);
        isLast = (old > 14.5f) ? 1 : 0;
    }
    __syncthreads();
    if (isLast && tid < 64) {
        __threadfence();
        int b2 = tid & 15, which = tid >> 4;
        float v = __hip_atomic_load(accp(xb,b2,1030 + which),
                                    __ATOMIC_RELAXED, __HIP_MEMORY_SCOPE_AGENT);
        for (int off = 1; off < 16; off <<= 1) v += __shfl_xor(v, off);
        float ct = __shfl(v, 0);
        float o1 = __shfl(v, 16);
        float mc = __shfl(v, 32);
        float o2 = __shfl(v, 48);
        if (tid == 0) {
            outp[160] = ct/16.f + sqrtf(fmaxf(o1, 0.f));
            outp[161] = mc/16.f + o2/16.f;
        }
    }
}

extern "C" void kernel_launch(void* const* d_in, const int* in_sizes, int n_in,
                              void* d_out, int out_size, void* d_ws, size_t ws_size,
                              hipStream_t stream)
{
    float* xb        = (float*)d_in[0];   // x, reused as scratch (restored by harness)
    const float* adj = (const float*)d_in[1];   // READ-ONLY
    const float* W_lin1 = (const float*)d_in[3];
    const float* b_lin1 = (const float*)d_in[4];
    const float* W_pool1= (const float*)d_in[5];
    const float* b_pool1= (const float*)d_in[6];
    const float* W_pool2= (const float*)d_in[7];
    const float* b_pool2= (const float*)d_in[8];
    const float* Wrel1  = (const float*)d_in[9];
    const float* brel1  = (const float*)d_in[10];
    const float* Wroot1 = (const float*)d_in[11];
    const float* Wrel2  = (const float*)d_in[12];
    const float* brel2  = (const float*)d_in[13];
    const float* Wroot2 = (const float*)d_in[14];
    const float* W_lin2 = (const float*)d_in[15];
    const float* b_lin2 = (const float*)d_in[16];
    const float* W_lin3 = (const float*)d_in[17];
    const float* b_lin3 = (const float*)d_in[18];
    u32* anb = (u32*)d_ws;   // exactly 32 MB, fully overwritten by k_c
    (void)ws_size; (void)in_sizes; (void)n_in; (void)out_size;

    k_a<<<dim3(1024),      dim3(256), 0, stream>>>(xb, W_lin1, b_lin1, W_pool1, b_pool1);
    k_c<<<dim3(8,16,16),   dim3(256), 0, stream>>>(adj, xb, anb);
    k_yd<<<dim3(32,16),    dim3(256), 0, stream>>>(anb, xb, Wrel1, brel1, Wroot1,
                                                   W_pool2, b_pool2);
    k_e<<<dim3(8,16,16),   dim3(256), 0, stream>>>(anb, xb);
    k_f1<<<dim3(16),       dim3(256), 0, stream>>>(xb, Wrel2, brel2, Wroot2,
                                                   W_lin2, b_lin2, W_lin3, b_lin3,
                                                   (float*)d_out);
}